// Round 6
// baseline (11003.307 us; speedup 1.0000x reference)
//
#include <hip/hip_runtime.h>

// ---------------- problem constants ----------------
constexpr int N  = 325;   // nodes
constexpr int B  = 64;    // batch
constexpr int T  = 12;    // encoder steps
constexpr int HZ = 12;    // decoder horizon
constexpr int U  = 64;    // rnn units
constexpr int BN = B * N; // 20800 rows

// SS = [S ; S^2] stacked: rows [0,325)=S, [336,661)=S^2, M=672 (42 tiles)
constexpr int SSTIL = 42;   // row tiles
constexpr int SSKC  = 11;   // K chunks of 32 (K padded 325->352)

constexpr int BLK  = 1024;  // one block per batch, 16 waves
constexpr int XST  = 364;   // u32 stride per feature column in LDS
constexpr int ZROWS = 336;  // per-batch zcat rows (padded to tiles)
constexpr int ZSTR  = 384;  // per-batch zcat row capacity (max K3P)

typedef __attribute__((ext_vector_type(8))) short short8;
typedef __attribute__((ext_vector_type(4))) float floatx4;

// bf16 round-to-nearest-even + hi/lo split helpers
__device__ inline unsigned short f2bf(float f) {
    unsigned u = __float_as_uint(f);
    u += 0x7fff + ((u >> 16) & 1);
    return (unsigned short)(u >> 16);
}
__device__ inline unsigned pack_hilo(float v) {
    const unsigned short hi = f2bf(v);
    const float hif = __uint_as_float(((unsigned)hi) << 16);
    const unsigned short lo = f2bf(v - hif);
    return (unsigned)hi | ((unsigned)lo << 16);
}
__device__ inline void unpack8(const uint4 u0, const uint4 u1,
                               short8& h, short8& l) {
    const unsigned uu[8] = {u0.x, u0.y, u0.z, u0.w, u1.x, u1.y, u1.z, u1.w};
    #pragma unroll
    for (int j = 0; j < 8; ++j) {
        h[j] = (short)(uu[j] & 0xffffu);
        l[j] = (short)(uu[j] >> 16);
    }
}

// ---------------- setup kernels ----------------

__global__ void zero_kernel(unsigned* __restrict__ p, long n) {
    long i = (long)blockIdx.x * blockDim.x + threadIdx.x;
    const long stride = (long)gridDim.x * blockDim.x;
    for (; i < n; i += stride) p[i] = 0u;
}

// S2 = S @ S (fp32). One block per output row.
__global__ __launch_bounds__(256)
void s2_build(const float* __restrict__ S, float* __restrict__ S2)
{
    const int m = blockIdx.x;
    __shared__ float srow[N];
    for (int i = threadIdx.x; i < N; i += 256) srow[i] = S[m * N + i];
    __syncthreads();
    for (int c = threadIdx.x; c < N; c += 256) {
        float a = 0.f;
        for (int k = 0; k < N; ++k) a += srow[k] * S[k * N + c];
        S2[m * N + c] = a;
    }
}

// Prepack SS=[S;S2] into MFMA A-fragments (bf16 hi/lo).
__global__ __launch_bounds__(64)
void prepack_ss(const float* __restrict__ S, const float* __restrict__ S2,
                short* __restrict__ ssh, short* __restrict__ ssl)
{
    const int t = blockIdx.x, kc = blockIdx.y, lane = threadIdx.x;
    const int quad = lane >> 4, l15 = lane & 15;
    short8 hv, lv;
    #pragma unroll
    for (int j = 0; j < 8; ++j) {
        const int m = t * 16 + l15;
        const int k = kc * 32 + quad * 8 + j;
        float v = 0.f;
        if (k < N) {
            if (m < N) v = S[m * N + k];
            else if (m >= 336 && m < 336 + N) v = S2[(m - 336) * N + k];
        }
        const unsigned short hb = f2bf(v);
        hv[j] = (short)hb;
        lv[j] = (short)f2bf(v - __uint_as_float(((unsigned)hb) << 16));
    }
    const size_t off = ((size_t)(t * SSKC + kc) * 64 + lane);
    ((short8*)ssh)[off] = hv;
    ((short8*)ssl)[off] = lv;
}

// Prepack weights (3F x Nout fp32, level-major) into MFMA B-fragment order,
// bf16 hi/lo, K padded to K3P, with Chebyshev fold:
//   W0' = W0 - W2, W1' = W1, W2' = 2*W2
__global__ __launch_bounds__(64)
void prepack_w(const float* __restrict__ W, short* __restrict__ Wh,
               short* __restrict__ Wl, int F, int Nout, int NT)
{
    const int kc = blockIdx.x, n = blockIdx.y, lane = threadIdx.x;
    const int quad = lane >> 4, l15 = lane & 15;
    short8 hv, lv;
    #pragma unroll
    for (int j = 0; j < 8; ++j) {
        const int k   = kc * 32 + quad * 8 + j;
        const int col = n * 16 + l15;
        const int lvl = k / F, f = k - lvl * F;
        float w = 0.f;
        if (lvl == 0)
            w = W[(size_t)f * Nout + col] - W[(size_t)(2 * F + f) * Nout + col];
        else if (lvl == 1)
            w = W[(size_t)(F + f) * Nout + col];
        else if (lvl == 2)
            w = 2.f * W[(size_t)(2 * F + f) * Nout + col];
        const unsigned short hb = f2bf(w);
        hv[j] = (short)hb;
        lv[j] = (short)f2bf(w - __uint_as_float(((unsigned)hb) << 16));
    }
    const size_t off = ((size_t)(kc * NT + n) * 64 + lane);
    ((short8*)Wh)[off] = hv;
    ((short8*)Wl)[off] = lv;
}

// ---------------- persistent per-batch kernel ----------------

struct MegaParams {
    const short8* ssh; const short8* ssl;
    const float*  inputs;
    float* h0; float* h1; float* dec_in; float* ru;
    unsigned* zcat;
    const short8* Wgh[4]; const short8* Wgl[4];
    const short8* Wch[4]; const short8* Wcl[4];
    const float* gb[4];  const float* cb[4];
    const float* pW; const float* pb;
    float* out;
};

// Diffusion phase: Y = SS @ X for this batch, chunked over feature columns
// through LDS. Writes packed z = [z0 | y1 | y2] into zb (row stride K3P).
template<int DIN, int F, int K3P, bool RMUL, int CHW>
__device__ __forceinline__ void d_phase(const MegaParams& P,
    const float* __restrict__ x, const float* __restrict__ h,
    unsigned* __restrict__ zb, int b, unsigned* __restrict__ xls)
{
    constexpr int NCH = (F + CHW - 1) / CHW;
    constexpr int CTS = CHW / 16;
    const int tid = threadIdx.x, wave = tid >> 6, lane = tid & 63;
    const int quad = lane >> 4, l15 = lane & 15;

    for (int c = 0; c < NCH; ++c) {
        const int c0 = c * CHW;
        __syncthreads();   // previous phase / previous chunk done with xls
        // stage X chunk (packed bf16 hi/lo) col-major; write z0 section
        for (int idx = tid; idx < 352 * CHW; idx += BLK) {
            const int n = idx / CHW, f = idx - n * CHW, gf = c0 + f;
            unsigned u = 0u;
            if (n < N && gf < F) {
                const int row = b * N + n;
                float v;
                if (gf < DIN) {
                    v = x[(size_t)row * DIN + gf];
                } else {
                    v = h[(size_t)row * U + (gf - DIN)];
                    if (RMUL) v *= P.ru[(size_t)row * 128 + (gf - DIN)];
                }
                u = pack_hilo(v);
                if (!(RMUL && gf < DIN))   // x-part identical to gate pass
                    zb[(size_t)n * K3P + gf] = u;
            }
            xls[f * XST + n] = u;
        }
        __syncthreads();
        // MFMA: 42 row tiles x CTS col tiles
        for (int rt = wave; rt < SSTIL; rt += 16) {
            floatx4 acc[CTS];
            #pragma unroll
            for (int ct = 0; ct < CTS; ++ct) acc[ct] = (floatx4){0.f, 0.f, 0.f, 0.f};
            for (int kc = 0; kc < SSKC; ++kc) {
                const size_t fo = (size_t)(rt * SSKC + kc) * 64 + lane;
                const short8 ah = P.ssh[fo], al = P.ssl[fo];
                const int koff = kc * 32 + quad * 8;
                #pragma unroll
                for (int ct = 0; ct < CTS; ++ct) {
                    const uint4 u0 = *(const uint4*)&xls[(ct * 16 + l15) * XST + koff];
                    const uint4 u1 = *(const uint4*)&xls[(ct * 16 + l15) * XST + koff + 4];
                    short8 bh, bl;
                    unpack8(u0, u1, bh, bl);
                    acc[ct] = __builtin_amdgcn_mfma_f32_16x16x32_bf16(ah, bh, acc[ct], 0, 0, 0);
                    acc[ct] = __builtin_amdgcn_mfma_f32_16x16x32_bf16(ah, bl, acc[ct], 0, 0, 0);
                    acc[ct] = __builtin_amdgcn_mfma_f32_16x16x32_bf16(al, bh, acc[ct], 0, 0, 0);
                }
            }
            // epilogue: rows <325 -> y1 (sect F); rows 336..660 -> y2 (sect 2F)
            #pragma unroll
            for (int ct = 0; ct < CTS; ++ct) {
                const int col = c0 + ct * 16 + l15;
                if (col >= F) continue;
                #pragma unroll
                for (int r = 0; r < 4; ++r) {
                    const int m = rt * 16 + quad * 4 + r;
                    if (m < N)
                        zb[(size_t)m * K3P + F + col] = pack_hilo(acc[ct][r]);
                    else if (m >= 336 && m < 336 + N)
                        zb[(size_t)(m - 336) * K3P + 2 * F + col] = pack_hilo(acc[ct][r]);
                }
            }
        }
    }
}

// Gate phase: ru = sigmoid(z @ Wg + b), 128 cols.
template<int K3P>
__device__ __forceinline__ void g_phase(const MegaParams& P,
    const unsigned* __restrict__ zb, const short8* __restrict__ Wh,
    const short8* __restrict__ Wl, const float* __restrict__ bias, int b)
{
    constexpr int NT = 8, KC = K3P >> 5;
    const int tid = threadIdx.x, wave = tid >> 6, lane = tid & 63;
    const int quad = lane >> 4, l15 = lane & 15;

    for (int rt = wave; rt < 21; rt += 16) {
        const int row0 = rt * 16;
        floatx4 acc[NT];
        #pragma unroll
        for (int n = 0; n < NT; ++n) {
            const float bv = bias[n * 16 + l15];
            acc[n] = (floatx4){bv, bv, bv, bv};
        }
        const unsigned* __restrict__ zrow = zb + (size_t)(row0 + l15) * K3P + quad * 8;
        for (int kc = 0; kc < KC; ++kc) {
            const uint4* p = (const uint4*)(zrow + kc * 32);
            short8 ahi, alo;
            unpack8(p[0], p[1], ahi, alo);
            const short8* __restrict__ wh = Wh + (size_t)(kc * NT) * 64 + lane;
            const short8* __restrict__ wl = Wl + (size_t)(kc * NT) * 64 + lane;
            #pragma unroll
            for (int n = 0; n < NT; ++n) {
                const short8 bh = wh[n * 64], bl = wl[n * 64];
                acc[n] = __builtin_amdgcn_mfma_f32_16x16x32_bf16(ahi, bh, acc[n], 0, 0, 0);
                acc[n] = __builtin_amdgcn_mfma_f32_16x16x32_bf16(ahi, bl, acc[n], 0, 0, 0);
                acc[n] = __builtin_amdgcn_mfma_f32_16x16x32_bf16(alo, bh, acc[n], 0, 0, 0);
            }
        }
        #pragma unroll
        for (int n = 0; n < NT; ++n) {
            const int col = n * 16 + l15;
            #pragma unroll
            for (int r = 0; r < 4; ++r) {
                const int row = row0 + quad * 4 + r;
                if (row < N)
                    P.ru[(size_t)(b * N + row) * 128 + col] =
                        1.f / (1.f + __expf(-acc[n][r]));
            }
        }
    }
}

// Candidate phase: c = tanh(z @ Wc + b); h = u*h + (1-u)*c; optional proj.
template<int K3P, bool PROJ>
__device__ __forceinline__ void c_phase(const MegaParams& P,
    const unsigned* __restrict__ zb, const short8* __restrict__ Wh,
    const short8* __restrict__ Wl, const float* __restrict__ bias,
    float* __restrict__ h, int b, float* __restrict__ outp)
{
    constexpr int NT = 4, KC = K3P >> 5;
    const int tid = threadIdx.x, wave = tid >> 6, lane = tid & 63;
    const int quad = lane >> 4, l15 = lane & 15;

    for (int rt = wave; rt < 21; rt += 16) {
        const int row0 = rt * 16;
        floatx4 acc[NT];
        #pragma unroll
        for (int n = 0; n < NT; ++n) {
            const float bv = bias[n * 16 + l15];
            acc[n] = (floatx4){bv, bv, bv, bv};
        }
        const unsigned* __restrict__ zrow = zb + (size_t)(row0 + l15) * K3P + quad * 8;
        for (int kc = 0; kc < KC; ++kc) {
            const uint4* p = (const uint4*)(zrow + kc * 32);
            short8 ahi, alo;
            unpack8(p[0], p[1], ahi, alo);
            const short8* __restrict__ wh = Wh + (size_t)(kc * NT) * 64 + lane;
            const short8* __restrict__ wl = Wl + (size_t)(kc * NT) * 64 + lane;
            #pragma unroll
            for (int n = 0; n < NT; ++n) {
                const short8 bh = wh[n * 64], bl = wl[n * 64];
                acc[n] = __builtin_amdgcn_mfma_f32_16x16x32_bf16(ahi, bh, acc[n], 0, 0, 0);
                acc[n] = __builtin_amdgcn_mfma_f32_16x16x32_bf16(ahi, bl, acc[n], 0, 0, 0);
                acc[n] = __builtin_amdgcn_mfma_f32_16x16x32_bf16(alo, bh, acc[n], 0, 0, 0);
            }
        }
        float pr[4] = {0.f, 0.f, 0.f, 0.f};
        #pragma unroll
        for (int n = 0; n < NT; ++n) {
            const int col = n * 16 + l15;
            float pw = 0.f;
            if constexpr (PROJ) pw = P.pW[col];
            #pragma unroll
            for (int r = 0; r < 4; ++r) {
                const int row = row0 + quad * 4 + r;
                if (row < N) {
                    const size_t grow = (size_t)(b * N + row);
                    const float cc = tanhf(acc[n][r]);
                    const float ug = P.ru[grow * 128 + 64 + col];  // u
                    const float hv = h[grow * 64 + col];
                    const float hn = ug * hv + (1.f - ug) * cc;
                    h[grow * 64 + col] = hn;
                    if constexpr (PROJ) pr[r] += hn * pw;
                }
            }
        }
        if constexpr (PROJ) {
            #pragma unroll
            for (int r = 0; r < 4; ++r) {
                float v = pr[r];
                v += __shfl_xor(v, 1); v += __shfl_xor(v, 2);
                v += __shfl_xor(v, 4); v += __shfl_xor(v, 8);
                if (l15 == 0) {
                    const int row = row0 + quad * 4 + r;
                    if (row < N) {
                        const float o = v + P.pb[0];
                        outp[b * N + row]     = o;
                        P.dec_in[b * N + row] = o;
                    }
                }
            }
        }
    }
}

__global__ __launch_bounds__(BLK, 1)
void mega_kernel(MegaParams P)
{
    __shared__ __align__(16) unsigned xls[80 * XST];   // 116.5 KB
    const int b = blockIdx.x;
    unsigned* zb = P.zcat + (size_t)b * ZROWS * ZSTR;

    // -------- encoder --------
    for (int t = 0; t < T; ++t) {
        const float* x = P.inputs + (size_t)t * BN * 2;
        // layer 0: DIN=2, F=66, K3P=224, one 80-col chunk
        d_phase<2, 66, 224, false, 80>(P, x, P.h0, zb, b, xls);
        __syncthreads();
        g_phase<224>(P, zb, P.Wgh[0], P.Wgl[0], P.gb[0], b);
        __syncthreads();
        d_phase<2, 66, 224, true, 80>(P, x, P.h0, zb, b, xls);
        __syncthreads();
        c_phase<224, false>(P, zb, P.Wch[0], P.Wcl[0], P.cb[0], P.h0, b, nullptr);
        __syncthreads();
        // layer 1: DIN=64, F=128, K3P=384, two 64-col chunks
        d_phase<64, 128, 384, false, 64>(P, P.h0, P.h1, zb, b, xls);
        __syncthreads();
        g_phase<384>(P, zb, P.Wgh[1], P.Wgl[1], P.gb[1], b);
        __syncthreads();
        d_phase<64, 128, 384, true, 64>(P, P.h0, P.h1, zb, b, xls);
        __syncthreads();
        c_phase<384, false>(P, zb, P.Wch[1], P.Wcl[1], P.cb[1], P.h1, b, nullptr);
        __syncthreads();
    }
    // -------- decoder --------
    for (int hz = 0; hz < HZ; ++hz) {
        // layer 0: DIN=1, F=65, K3P=224
        d_phase<1, 65, 224, false, 80>(P, P.dec_in, P.h0, zb, b, xls);
        __syncthreads();
        g_phase<224>(P, zb, P.Wgh[2], P.Wgl[2], P.gb[2], b);
        __syncthreads();
        d_phase<1, 65, 224, true, 80>(P, P.dec_in, P.h0, zb, b, xls);
        __syncthreads();
        c_phase<224, false>(P, zb, P.Wch[2], P.Wcl[2], P.cb[2], P.h0, b, nullptr);
        __syncthreads();
        // layer 1 + fused projection
        d_phase<64, 128, 384, false, 64>(P, P.h0, P.h1, zb, b, xls);
        __syncthreads();
        g_phase<384>(P, zb, P.Wgh[3], P.Wgl[3], P.gb[3], b);
        __syncthreads();
        d_phase<64, 128, 384, true, 64>(P, P.h0, P.h1, zb, b, xls);
        __syncthreads();
        c_phase<384, true>(P, zb, P.Wch[3], P.Wcl[3], P.cb[3], P.h1, b,
                           P.out + (size_t)hz * BN);
        __syncthreads();
    }
}

// ---------------- host launcher ----------------

extern "C" void kernel_launch(void* const* d_in, const int* in_sizes, int n_in,
                              void* d_out, int out_size, void* d_ws, size_t ws_size,
                              hipStream_t stream)
{
    const float* inputs = (const float*)d_in[0];
    const float* S      = (const float*)d_in[1];
    const float* Wt[4][4];
    for (int l = 0; l < 4; ++l)
        for (int j = 0; j < 4; ++j)
            Wt[l][j] = (const float*)d_in[2 + l * 4 + j];
    const float* pW = (const float*)d_in[18];
    const float* pb = (const float*)d_in[19];
    float* out = (float*)d_out;

    // workspace layout
    float*    ws     = (float*)d_ws;
    float*    h0     = ws;                        // BN*64
    float*    h1     = h0 + (size_t)BN * U;       // BN*64
    float*    dec_in = h1 + (size_t)BN * U;       // BN
    float*    ru     = dec_in + BN;               // BN*128
    unsigned* zcat   = (unsigned*)(ru + (size_t)BN * 128);  // B*336*384
    float*    S2     = (float*)(zcat + (size_t)B * ZROWS * ZSTR);  // N*N
    char*     pp     = (char*)(S2 + (size_t)N * N);
    pp = (char*)(((uintptr_t)pp + 15) & ~(uintptr_t)15);

    short* ssh = (short*)pp;                      // 42*11*64*8 shorts
    short* ssl = ssh + (size_t)SSTIL * SSKC * 64 * 8;
    char*  wpbase = (char*)(ssl + (size_t)SSTIL * SSKC * 64 * 8);

    const int Fs[4]   = {66, 128, 65, 128};
    const int K3ps[4] = {224, 384, 224, 384};
    short *Wgh[4], *Wgl[4], *Wch[4], *Wcl[4];
    size_t off = 0;
    for (int l = 0; l < 4; ++l) {
        const size_t ge = (size_t)K3ps[l] * 128, ce = (size_t)K3ps[l] * 64;
        Wgh[l] = (short*)(wpbase + off); off += ge * 2;
        Wgl[l] = (short*)(wpbase + off); off += ge * 2;
        Wch[l] = (short*)(wpbase + off); off += ce * 2;
        Wcl[l] = (short*)(wpbase + off); off += ce * 2;
    }

    // zero state + zcat (pad rows/strips must be finite-zero; re-done per replay)
    const long zn = (long)BN * (U + U + 128) + BN + (long)B * ZROWS * ZSTR;
    zero_kernel<<<2048, 256, 0, stream>>>((unsigned*)h0, zn);

    s2_build<<<N, 256, 0, stream>>>(S, S2);
    prepack_ss<<<dim3(SSTIL, SSKC), 64, 0, stream>>>(S, S2, ssh, ssl);
    for (int l = 0; l < 4; ++l) {
        prepack_w<<<dim3(K3ps[l] / 32, 8), 64, 0, stream>>>(Wt[l][0], Wgh[l], Wgl[l],
                                                            Fs[l], 128, 8);
        prepack_w<<<dim3(K3ps[l] / 32, 4), 64, 0, stream>>>(Wt[l][2], Wch[l], Wcl[l],
                                                            Fs[l], 64, 4);
    }

    MegaParams P;
    P.ssh = (const short8*)ssh; P.ssl = (const short8*)ssl;
    P.inputs = inputs;
    P.h0 = h0; P.h1 = h1; P.dec_in = dec_in; P.ru = ru; P.zcat = zcat;
    for (int l = 0; l < 4; ++l) {
        P.Wgh[l] = (const short8*)Wgh[l]; P.Wgl[l] = (const short8*)Wgl[l];
        P.Wch[l] = (const short8*)Wch[l]; P.Wcl[l] = (const short8*)Wcl[l];
        P.gb[l] = Wt[l][1]; P.cb[l] = Wt[l][3];
    }
    P.pW = pW; P.pb = pb; P.out = out;

    mega_kernel<<<B, BLK, 0, stream>>>(P);
}

// Round 7
// 10608.515 us; speedup vs baseline: 1.0372x; 1.0372x over previous
//
#include <hip/hip_runtime.h>

// ---------------- problem constants ----------------
constexpr int N  = 325;   // nodes
constexpr int B  = 64;    // batch
constexpr int T  = 12;    // encoder steps
constexpr int HZ = 12;    // decoder horizon
constexpr int U  = 64;    // rnn units
constexpr int BN = B * N; // 20800 rows

// SS = [S ; S^2] stacked: rows [0,325)=S, [336,661)=S^2 (42 tiles of 16)
constexpr int SSTIL = 42;
constexpr int SSKC  = 11;   // K chunks of 32 (K padded 325->352)

typedef __attribute__((ext_vector_type(8))) short short8;
typedef __attribute__((ext_vector_type(4))) float floatx4;

// bf16 round-to-nearest-even + hi/lo split helpers
__device__ inline unsigned short f2bf(float f) {
    unsigned u = __float_as_uint(f);
    u += 0x7fff + ((u >> 16) & 1);
    return (unsigned short)(u >> 16);
}
__device__ inline unsigned pack_hilo(float v) {
    const unsigned short hi = f2bf(v);
    const float hif = __uint_as_float(((unsigned)hi) << 16);
    const unsigned short lo = f2bf(v - hif);
    return (unsigned)hi | ((unsigned)lo << 16);
}
__device__ inline void unpack8(const uint4 u0, const uint4 u1,
                               short8& h, short8& l) {
    const unsigned uu[8] = {u0.x, u0.y, u0.z, u0.w, u1.x, u1.y, u1.z, u1.w};
    #pragma unroll
    for (int j = 0; j < 8; ++j) {
        h[j] = (short)(uu[j] & 0xffffu);
        l[j] = (short)(uu[j] >> 16);
    }
}

// ---------------- setup kernels ----------------

__global__ void zero_kernel(unsigned* __restrict__ p, long n) {
    long i = (long)blockIdx.x * blockDim.x + threadIdx.x;
    const long stride = (long)gridDim.x * blockDim.x;
    for (; i < n; i += stride) p[i] = 0u;
}

// S2 = S @ S (fp32). One block per output row.
__global__ __launch_bounds__(256)
void s2_build(const float* __restrict__ S, float* __restrict__ S2)
{
    const int m = blockIdx.x;
    __shared__ float srow[N];
    for (int i = threadIdx.x; i < N; i += 256) srow[i] = S[m * N + i];
    __syncthreads();
    for (int c = threadIdx.x; c < N; c += 256) {
        float a = 0.f;
        for (int k = 0; k < N; ++k) a += srow[k] * S[k * N + c];
        S2[m * N + c] = a;
    }
}

// Prepack SS=[S;S2] into MFMA A-fragments (bf16 hi/lo).
// A-frag: lane l holds A[row = t*16 + (l&15)][k = kc*32 + (l>>4)*8 + j].
__global__ __launch_bounds__(64)
void prepack_ss(const float* __restrict__ S, const float* __restrict__ S2,
                short* __restrict__ ssh, short* __restrict__ ssl)
{
    const int t = blockIdx.x, kc = blockIdx.y, lane = threadIdx.x;
    const int quad = lane >> 4, l15 = lane & 15;
    short8 hv, lv;
    #pragma unroll
    for (int j = 0; j < 8; ++j) {
        const int m = t * 16 + l15;
        const int k = kc * 32 + quad * 8 + j;
        float v = 0.f;
        if (k < N) {
            if (m < N) v = S[m * N + k];
            else if (m >= 336 && m < 336 + N) v = S2[(m - 336) * N + k];
        }
        const unsigned short hb = f2bf(v);
        hv[j] = (short)hb;
        lv[j] = (short)f2bf(v - __uint_as_float(((unsigned)hb) << 16));
    }
    const size_t off = ((size_t)(t * SSKC + kc) * 64 + lane);
    ((short8*)ssh)[off] = hv;
    ((short8*)ssl)[off] = lv;
}

// Prepack weights (3F x Nout fp32, level-major) into MFMA B-fragment order,
// bf16 hi/lo, K padded to K3P, Chebyshev fold: W0'=W0-W2, W1'=W1, W2'=2*W2.
__global__ __launch_bounds__(64)
void prepack_w(const float* __restrict__ W, short* __restrict__ Wh,
               short* __restrict__ Wl, int F, int Nout, int NT)
{
    const int kc = blockIdx.x, n = blockIdx.y, lane = threadIdx.x;
    const int quad = lane >> 4, l15 = lane & 15;
    short8 hv, lv;
    #pragma unroll
    for (int j = 0; j < 8; ++j) {
        const int k   = kc * 32 + quad * 8 + j;
        const int col = n * 16 + l15;
        const int lvl = k / F, f = k - lvl * F;
        float w = 0.f;
        if (lvl == 0)
            w = W[(size_t)f * Nout + col] - W[(size_t)(2 * F + f) * Nout + col];
        else if (lvl == 1)
            w = W[(size_t)(F + f) * Nout + col];
        else if (lvl == 2)
            w = 2.f * W[(size_t)(2 * F + f) * Nout + col];
        const unsigned short hb = f2bf(w);
        hv[j] = (short)hb;
        lv[j] = (short)f2bf(w - __uint_as_float(((unsigned)hb) << 16));
    }
    const size_t off = ((size_t)(kc * NT + n) * 64 + lane);
    ((short8*)Wh)[off] = hv;
    ((short8*)Wl)[off] = lv;
}

// ---------------- fused cell kernel ----------------
// Block = (row-tile bx in [0,21), batch b). 256 threads / 4 waves.
// Phase A: y1 = S@X, y2 = S^2@X for the block's 16 output rows across ALL F
//   columns, K-chunked through LDS (xls). z = [z0|y1|y2] assembled in LDS.
// Phase B: GEMM z @ W for these 16 rows.
//   GATE: ru = sigmoid(.) (128 cols, 2 tiles/wave)
//   CAND: c = tanh(.); h_new = u*h_old + (1-u)*c (64 cols, 1 tile/wave);
//         optional fused projection -> out, dec_in.
template<int DIN, int F, int K3P, bool RMUL, bool GATE, bool PROJ>
__global__ __launch_bounds__(256)
void fused_cell(const short8* __restrict__ ssh, const short8* __restrict__ ssl,
                const float* __restrict__ x, const float* __restrict__ hin,
                const float* __restrict__ ru, const short8* __restrict__ Wh,
                const short8* __restrict__ Wl, const float* __restrict__ bias,
                float* __restrict__ ruout, float* __restrict__ hout,
                const float* __restrict__ pW, const float* __restrict__ pb,
                float* __restrict__ outp, float* __restrict__ dec_in)
{
    constexpr int CT  = (F + 15) / 16;   // col tiles in diffusion
    constexpr int FP  = CT * 16;         // padded cols
    constexpr int ZP  = K3P + 4;         // z row pitch (u32), 16B-aligned rows
    constexpr int KC  = K3P / 32;        // GEMM K chunks
    constexpr int KF3 = 3 * F;
    constexpr int NTW = GATE ? 8 : 4;    // weight col tiles total
    constexpr int NTQ = GATE ? 2 : 1;    // col tiles per wave in GEMM

    const int bx = blockIdx.x, b = blockIdx.y;
    const int tid = threadIdx.x, wave = tid >> 6, lane = tid & 63;
    const int quad = lane >> 4, l15 = lane & 15;

    __shared__ __align__(16) unsigned xls[FP * 36];
    __shared__ __align__(16) unsigned zls[16 * ZP];
    __shared__ float prbuf[4][16];

    const int rt1 = bx, rt2 = bx + 21;

    floatx4 dacc[2][2];
    #pragma unroll
    for (int i = 0; i < 2; ++i)
        #pragma unroll
        for (int q = 0; q < 2; ++q) dacc[i][q] = (floatx4){0.f, 0.f, 0.f, 0.f};

    // ---- Phase A: diffusion over K chunks of 32 nodes ----
    for (int kc = 0; kc < SSKC; ++kc) {
        __syncthreads();   // previous chunk's MFMA reads done
        for (int idx = tid; idx < 32 * FP; idx += 256) {
            const int n = idx / FP, f = idx - n * FP;
            const int node = kc * 32 + n;
            unsigned u = 0u;
            if (node < N && f < F) {
                const int row = b * N + node;
                float v = (f < DIN) ? x[(size_t)row * DIN + f]
                                    : hin[(size_t)row * U + (f - DIN)];
                if (RMUL && f >= DIN) v *= ru[(size_t)row * 128 + (f - DIN)];
                u = pack_hilo(v);
            }
            xls[f * 36 + n] = u;
        }
        __syncthreads();
        const size_t fo1 = (size_t)(rt1 * SSKC + kc) * 64 + lane;
        const size_t fo2 = (size_t)(rt2 * SSKC + kc) * 64 + lane;
        const short8 a1h = ssh[fo1], a1l = ssl[fo1];
        const short8 a2h = ssh[fo2], a2l = ssl[fo2];
        #pragma unroll
        for (int q = 0; q < 2; ++q) {
            const int ct = wave * 2 + q;
            if (ct < CT) {
                const int base = (ct * 16 + l15) * 36 + quad * 8;
                const uint4 u0 = *(const uint4*)&xls[base];
                const uint4 u1 = *(const uint4*)&xls[base + 4];
                short8 bh, bl;
                unpack8(u0, u1, bh, bl);
                dacc[0][q] = __builtin_amdgcn_mfma_f32_16x16x32_bf16(a1h, bh, dacc[0][q], 0, 0, 0);
                dacc[0][q] = __builtin_amdgcn_mfma_f32_16x16x32_bf16(a1h, bl, dacc[0][q], 0, 0, 0);
                dacc[0][q] = __builtin_amdgcn_mfma_f32_16x16x32_bf16(a1l, bh, dacc[0][q], 0, 0, 0);
                dacc[1][q] = __builtin_amdgcn_mfma_f32_16x16x32_bf16(a2h, bh, dacc[1][q], 0, 0, 0);
                dacc[1][q] = __builtin_amdgcn_mfma_f32_16x16x32_bf16(a2h, bl, dacc[1][q], 0, 0, 0);
                dacc[1][q] = __builtin_amdgcn_mfma_f32_16x16x32_bf16(a2l, bh, dacc[1][q], 0, 0, 0);
            }
        }
    }

    // ---- assemble z in LDS: y sections from accumulators ----
    #pragma unroll
    for (int q = 0; q < 2; ++q) {
        const int ct = wave * 2 + q;
        if (ct < CT) {
            const int col = ct * 16 + l15;
            if (col < F) {
                #pragma unroll
                for (int r = 0; r < 4; ++r) {
                    const int zr = quad * 4 + r;
                    zls[zr * ZP + F + col]     = pack_hilo(dacc[0][q][r]);
                    zls[zr * ZP + 2 * F + col] = pack_hilo(dacc[1][q][r]);
                }
            }
        }
    }
    // z0 section + K padding
    for (int idx = tid; idx < 16 * F; idx += 256) {
        const int r = idx / F, f = idx - r * F;
        const int m = bx * 16 + r;
        unsigned u = 0u;
        if (m < N) {
            const int row = b * N + m;
            float v = (f < DIN) ? x[(size_t)row * DIN + f]
                                : hin[(size_t)row * U + (f - DIN)];
            if (RMUL && f >= DIN) v *= ru[(size_t)row * 128 + (f - DIN)];
            u = pack_hilo(v);
        }
        zls[r * ZP + f] = u;
    }
    constexpr int PAD = K3P - KF3;
    for (int idx = tid; idx < 16 * PAD; idx += 256) {
        const int r = idx / PAD, c = idx - r * PAD;
        zls[r * ZP + KF3 + c] = 0u;
    }
    __syncthreads();

    // ---- Phase B: GEMM z @ W ----
    floatx4 gacc[NTQ];
    #pragma unroll
    for (int q = 0; q < NTQ; ++q) {
        const int nt = GATE ? (wave * 2 + q) : wave;
        const float bv = bias[nt * 16 + l15];
        gacc[q] = (floatx4){bv, bv, bv, bv};
    }
    for (int kc = 0; kc < KC; ++kc) {
        const int base = l15 * ZP + kc * 32 + quad * 8;
        const uint4 u0 = *(const uint4*)&zls[base];
        const uint4 u1 = *(const uint4*)&zls[base + 4];
        short8 ahi, alo;
        unpack8(u0, u1, ahi, alo);
        #pragma unroll
        for (int q = 0; q < NTQ; ++q) {
            const int nt = GATE ? (wave * 2 + q) : wave;
            const short8 bh = Wh[(size_t)(kc * NTW + nt) * 64 + lane];
            const short8 bl = Wl[(size_t)(kc * NTW + nt) * 64 + lane];
            gacc[q] = __builtin_amdgcn_mfma_f32_16x16x32_bf16(ahi, bh, gacc[q], 0, 0, 0);
            gacc[q] = __builtin_amdgcn_mfma_f32_16x16x32_bf16(ahi, bl, gacc[q], 0, 0, 0);
            gacc[q] = __builtin_amdgcn_mfma_f32_16x16x32_bf16(alo, bh, gacc[q], 0, 0, 0);
        }
    }

    // ---- epilogue ----
    if constexpr (GATE) {
        #pragma unroll
        for (int q = 0; q < NTQ; ++q) {
            const int col = (wave * 2 + q) * 16 + l15;
            #pragma unroll
            for (int r = 0; r < 4; ++r) {
                const int m = bx * 16 + quad * 4 + r;
                if (m < N)
                    ruout[(size_t)(b * N + m) * 128 + col] =
                        1.f / (1.f + __expf(-gacc[q][r]));
            }
        }
    } else {
        const int col = wave * 16 + l15;
        float pr[4] = {0.f, 0.f, 0.f, 0.f};
        #pragma unroll
        for (int r = 0; r < 4; ++r) {
            const int m = bx * 16 + quad * 4 + r;
            if (m < N) {
                const size_t grow = (size_t)(b * N + m);
                const float cc = tanhf(gacc[0][r]);
                const float ug = ru[grow * 128 + 64 + col];  // u = ru[:,64:]
                const float hv = hin[grow * 64 + col];
                const float hn = ug * hv + (1.f - ug) * cc;
                hout[grow * 64 + col] = hn;
                if constexpr (PROJ) pr[r] = hn * pW[col];
            }
        }
        if constexpr (PROJ) {
            #pragma unroll
            for (int r = 0; r < 4; ++r) {
                float v = pr[r];
                v += __shfl_xor(v, 1); v += __shfl_xor(v, 2);
                v += __shfl_xor(v, 4); v += __shfl_xor(v, 8);
                if (l15 == 0) prbuf[wave][quad * 4 + r] = v;
            }
            __syncthreads();
            if (tid < 16) {
                const int m = bx * 16 + tid;
                if (m < N) {
                    const float o = prbuf[0][tid] + prbuf[1][tid] +
                                    prbuf[2][tid] + prbuf[3][tid] + pb[0];
                    outp[b * N + m]   = o;
                    dec_in[b * N + m] = o;
                }
            }
        }
    }
}

// ---------------- host launcher ----------------

extern "C" void kernel_launch(void* const* d_in, const int* in_sizes, int n_in,
                              void* d_out, int out_size, void* d_ws, size_t ws_size,
                              hipStream_t stream)
{
    const float* inputs = (const float*)d_in[0];
    const float* S      = (const float*)d_in[1];
    const float* Wt[4][4];
    for (int l = 0; l < 4; ++l)
        for (int j = 0; j < 4; ++j)
            Wt[l][j] = (const float*)d_in[2 + l * 4 + j];
    const float* pW = (const float*)d_in[18];
    const float* pb = (const float*)d_in[19];
    float* out = (float*)d_out;

    // workspace layout (no zcat; ping-pong hidden states)
    float*  ws     = (float*)d_ws;
    float*  h0a    = ws;                         // BN*64
    float*  h0b    = h0a + (size_t)BN * U;
    float*  h1a    = h0b + (size_t)BN * U;
    float*  h1b    = h1a + (size_t)BN * U;
    float*  dec_in = h1b + (size_t)BN * U;       // BN
    float*  ru     = dec_in + BN;                // BN*128
    float*  S2     = ru + (size_t)BN * 128;      // N*N
    char*   pp     = (char*)(S2 + (size_t)N * N);
    pp = (char*)(((uintptr_t)pp + 15) & ~(uintptr_t)15);

    short* ssh = (short*)pp;                     // 42*11*64*8 shorts
    short* ssl = ssh + (size_t)SSTIL * SSKC * 64 * 8;
    char*  wpbase = (char*)(ssl + (size_t)SSTIL * SSKC * 64 * 8);

    const int Fs[4]   = {66, 128, 65, 128};
    const int K3ps[4] = {224, 384, 224, 384};
    short *Wgh[4], *Wgl[4], *Wch[4], *Wcl[4];
    size_t off = 0;
    for (int l = 0; l < 4; ++l) {
        const size_t ge = (size_t)K3ps[l] * 128, ce = (size_t)K3ps[l] * 64;
        Wgh[l] = (short*)(wpbase + off); off += ge * 2;
        Wgl[l] = (short*)(wpbase + off); off += ge * 2;
        Wch[l] = (short*)(wpbase + off); off += ce * 2;
        Wcl[l] = (short*)(wpbase + off); off += ce * 2;
    }

    // zero hidden state / dec_in / ru (per replay)
    const long zn = (long)BN * (4 * U) + BN + (long)BN * 128;
    zero_kernel<<<2048, 256, 0, stream>>>((unsigned*)h0a, zn);

    s2_build<<<N, 256, 0, stream>>>(S, S2);
    prepack_ss<<<dim3(SSTIL, SSKC), 64, 0, stream>>>(S, S2, ssh, ssl);
    for (int l = 0; l < 4; ++l) {
        prepack_w<<<dim3(K3ps[l] / 32, 8), 64, 0, stream>>>(Wt[l][0], Wgh[l], Wgl[l],
                                                            Fs[l], 128, 8);
        prepack_w<<<dim3(K3ps[l] / 32, 4), 64, 0, stream>>>(Wt[l][2], Wch[l], Wcl[l],
                                                            Fs[l], 64, 4);
    }

    const short8* SSH = (const short8*)ssh;
    const short8* SSL = (const short8*)ssl;
    const dim3 grid(21, B);

    float* h0p[2] = {h0a, h0b};
    float* h1p[2] = {h1a, h1b};
    int p0 = 0, p1 = 0;

    // -------- encoder --------
    for (int t = 0; t < T; ++t) {
        const float* x = inputs + (size_t)t * BN * 2;
        fused_cell<2, 66, 224, false, true, false><<<grid, 256, 0, stream>>>(
            SSH, SSL, x, h0p[p0], ru, (short8*)Wgh[0], (short8*)Wgl[0], Wt[0][1],
            ru, nullptr, nullptr, nullptr, nullptr, nullptr);
        fused_cell<2, 66, 224, true, false, false><<<grid, 256, 0, stream>>>(
            SSH, SSL, x, h0p[p0], ru, (short8*)Wch[0], (short8*)Wcl[0], Wt[0][3],
            nullptr, h0p[p0 ^ 1], nullptr, nullptr, nullptr, nullptr);
        p0 ^= 1;
        fused_cell<64, 128, 384, false, true, false><<<grid, 256, 0, stream>>>(
            SSH, SSL, h0p[p0], h1p[p1], ru, (short8*)Wgh[1], (short8*)Wgl[1], Wt[1][1],
            ru, nullptr, nullptr, nullptr, nullptr, nullptr);
        fused_cell<64, 128, 384, true, false, false><<<grid, 256, 0, stream>>>(
            SSH, SSL, h0p[p0], h1p[p1], ru, (short8*)Wch[1], (short8*)Wcl[1], Wt[1][3],
            nullptr, h1p[p1 ^ 1], nullptr, nullptr, nullptr, nullptr);
        p1 ^= 1;
    }
    // -------- decoder --------
    for (int hz = 0; hz < HZ; ++hz) {
        fused_cell<1, 65, 224, false, true, false><<<grid, 256, 0, stream>>>(
            SSH, SSL, dec_in, h0p[p0], ru, (short8*)Wgh[2], (short8*)Wgl[2], Wt[2][1],
            ru, nullptr, nullptr, nullptr, nullptr, nullptr);
        fused_cell<1, 65, 224, true, false, false><<<grid, 256, 0, stream>>>(
            SSH, SSL, dec_in, h0p[p0], ru, (short8*)Wch[2], (short8*)Wcl[2], Wt[2][3],
            nullptr, h0p[p0 ^ 1], nullptr, nullptr, nullptr, nullptr);
        p0 ^= 1;
        fused_cell<64, 128, 384, false, true, false><<<grid, 256, 0, stream>>>(
            SSH, SSL, h0p[p0], h1p[p1], ru, (short8*)Wgh[3], (short8*)Wgl[3], Wt[3][1],
            ru, nullptr, nullptr, nullptr, nullptr, nullptr);
        fused_cell<64, 128, 384, true, false, true><<<grid, 256, 0, stream>>>(
            SSH, SSL, h0p[p0], h1p[p1], ru, (short8*)Wch[3], (short8*)Wcl[3], Wt[3][3],
            nullptr, h1p[p1 ^ 1], pW, pb, out + (size_t)hz * BN, dec_in);
        p1 ^= 1;
    }
}

// Round 8
// 4082.073 us; speedup vs baseline: 2.6955x; 2.5988x over previous
//
#include <hip/hip_runtime.h>

// ---------------- problem constants ----------------
constexpr int N  = 325;   // nodes
constexpr int B  = 64;    // batch
constexpr int T  = 12;    // encoder steps
constexpr int HZ = 12;    // decoder horizon
constexpr int U  = 64;    // rnn units
constexpr int BN = B * N; // 20800 rows

// SS = [S ; S^2] stacked: rows [0,325)=S, [336,661)=S^2 (42 tiles of 16)
constexpr int SSTIL = 42;
constexpr int SSKC  = 11;   // K chunks of 32 (K padded 325->352)
constexpr int XST   = 364;  // u32 stride per feature column in diffuse LDS

typedef __attribute__((ext_vector_type(8))) short short8;
typedef __attribute__((ext_vector_type(4))) float floatx4;

// bf16 round-to-nearest-even + hi/lo split helpers
__device__ inline unsigned short f2bf(float f) {
    unsigned u = __float_as_uint(f);
    u += 0x7fff + ((u >> 16) & 1);
    return (unsigned short)(u >> 16);
}
__device__ inline unsigned pack_hilo(float v) {
    const unsigned short hi = f2bf(v);
    const float hif = __uint_as_float(((unsigned)hi) << 16);
    const unsigned short lo = f2bf(v - hif);
    return (unsigned)hi | ((unsigned)lo << 16);
}
__device__ inline void unpack8(const uint4 u0, const uint4 u1,
                               short8& h, short8& l) {
    const unsigned uu[8] = {u0.x, u0.y, u0.z, u0.w, u1.x, u1.y, u1.z, u1.w};
    #pragma unroll
    for (int j = 0; j < 8; ++j) {
        h[j] = (short)(uu[j] & 0xffffu);
        l[j] = (short)(uu[j] >> 16);
    }
}

// ---------------- setup kernels ----------------

__global__ void zero_kernel(unsigned* __restrict__ p, long n) {
    long i = (long)blockIdx.x * blockDim.x + threadIdx.x;
    const long stride = (long)gridDim.x * blockDim.x;
    for (; i < n; i += stride) p[i] = 0u;
}

// S2 = S @ S (fp32). One block per output row.
__global__ __launch_bounds__(256)
void s2_build(const float* __restrict__ S, float* __restrict__ S2)
{
    const int m = blockIdx.x;
    __shared__ float srow[N];
    for (int i = threadIdx.x; i < N; i += 256) srow[i] = S[m * N + i];
    __syncthreads();
    for (int c = threadIdx.x; c < N; c += 256) {
        float a = 0.f;
        for (int k = 0; k < N; ++k) a += srow[k] * S[k * N + c];
        S2[m * N + c] = a;
    }
}

// Prepack SS=[S;S2] into MFMA A-fragments (bf16 hi/lo).
// A-frag: lane l holds A[row = t*16 + (l&15)][k = kc*32 + (l>>4)*8 + j].
__global__ __launch_bounds__(64)
void prepack_ss(const float* __restrict__ S, const float* __restrict__ S2,
                short* __restrict__ ssh, short* __restrict__ ssl)
{
    const int t = blockIdx.x, kc = blockIdx.y, lane = threadIdx.x;
    const int quad = lane >> 4, l15 = lane & 15;
    short8 hv, lv;
    #pragma unroll
    for (int j = 0; j < 8; ++j) {
        const int m = t * 16 + l15;
        const int k = kc * 32 + quad * 8 + j;
        float v = 0.f;
        if (k < N) {
            if (m < N) v = S[m * N + k];
            else if (m >= 336 && m < 336 + N) v = S2[(m - 336) * N + k];
        }
        const unsigned short hb = f2bf(v);
        hv[j] = (short)hb;
        lv[j] = (short)f2bf(v - __uint_as_float(((unsigned)hb) << 16));
    }
    const size_t off = ((size_t)(t * SSKC + kc) * 64 + lane);
    ((short8*)ssh)[off] = hv;
    ((short8*)ssl)[off] = lv;
}

// Prepack weights (3F x Nout fp32, level-major) into MFMA B-fragment order,
// bf16 hi/lo, K padded to K3P, Chebyshev fold: W0'=W0-W2, W1'=W1, W2'=2*W2.
__global__ __launch_bounds__(64)
void prepack_w(const float* __restrict__ W, short* __restrict__ Wh,
               short* __restrict__ Wl, int F, int Nout, int NT)
{
    const int kc = blockIdx.x, n = blockIdx.y, lane = threadIdx.x;
    const int quad = lane >> 4, l15 = lane & 15;
    short8 hv, lv;
    #pragma unroll
    for (int j = 0; j < 8; ++j) {
        const int k   = kc * 32 + quad * 8 + j;
        const int col = n * 16 + l15;
        const int lvl = k / F, f = k - lvl * F;
        float w = 0.f;
        if (lvl == 0)
            w = W[(size_t)f * Nout + col] - W[(size_t)(2 * F + f) * Nout + col];
        else if (lvl == 1)
            w = W[(size_t)(F + f) * Nout + col];
        else if (lvl == 2)
            w = 2.f * W[(size_t)(2 * F + f) * Nout + col];
        const unsigned short hb = f2bf(w);
        hv[j] = (short)hb;
        lv[j] = (short)f2bf(w - __uint_as_float(((unsigned)hb) << 16));
    }
    const size_t off = ((size_t)(kc * NT + n) * 64 + lane);
    ((short8*)Wh)[off] = hv;
    ((short8*)Wl)[off] = lv;
}

// ---------------- diffusion GEMM body (round-5 proven) ----------------
// Y = SS @ X_b for one (batch, 32-col feature chunk cx, M-half mh). X built on
// the fly from (x, h [, r]); writes packed z = [z0 | y1 | y2] sections of zcat.
// 448 threads = 7 waves; wave w owns 3 row tiles.
template<int DIN, int F, int K3P, bool RMUL>
__device__ __forceinline__ void diffuse_body(
    const short8* __restrict__ ssh, const short8* __restrict__ ssl,
    const float* __restrict__ x, const float* __restrict__ h,
    const float* __restrict__ ru, unsigned* __restrict__ zcat,
    int cx, int b, int mh, unsigned* __restrict__ xls)
{
    const int c0 = cx * 32;
    const int tid = threadIdx.x, wave = tid >> 6, lane = tid & 63;
    const int quad = lane >> 4, l15 = lane & 15;

    // stage X chunk: global side coalesced (f fastest); LDS col-major write.
    // z0 section written by half-0 blocks only (identical data).
    for (int idx = tid; idx < 352 * 32; idx += 448) {
        const int n = idx >> 5, f = idx & 31, gf = c0 + f;
        unsigned u = 0u;
        if (n < N && gf < F) {
            const int row = b * N + n;
            float v;
            if (gf < DIN) {
                v = x[(size_t)row * DIN + gf];
            } else {
                v = h[(size_t)row * U + (gf - DIN)];
                if (RMUL) v *= ru[(size_t)row * 128 + (gf - DIN)];  // r = ru[:,:64]
            }
            u = pack_hilo(v);
            if (mh == 0 && !(RMUL && gf < DIN))  // x-part identical to gate pass
                zcat[(size_t)row * K3P + gf] = u;
        }
        xls[f * XST + n] = u;
    }
    __syncthreads();

    const int tb = mh * 21 + wave * 3;  // 3 row tiles per wave

    floatx4 acc[3][2];
    #pragma unroll
    for (int i = 0; i < 3; ++i)
        #pragma unroll
        for (int n = 0; n < 2; ++n)
            acc[i][n] = (floatx4){0.f, 0.f, 0.f, 0.f};

    // A-fragment double buffer: prefetch kc+1 while MFMAing kc
    short8 cah[3], cal[3], nah[3], nal[3];
    #pragma unroll
    for (int i = 0; i < 3; ++i) {
        const size_t fo = (size_t)((tb + i) * SSKC) * 64 + lane;
        cah[i] = ssh[fo]; cal[i] = ssl[fo];
    }
    for (int kc = 0; kc < SSKC; ++kc) {
        if (kc + 1 < SSKC) {
            #pragma unroll
            for (int i = 0; i < 3; ++i) {
                const size_t fo = (size_t)((tb + i) * SSKC + kc + 1) * 64 + lane;
                nah[i] = ssh[fo]; nal[i] = ssl[fo];
            }
        }
        short8 bh[2], bl[2];
        const int koff = kc * 32 + quad * 8;
        #pragma unroll
        for (int n = 0; n < 2; ++n) {
            const uint4 u0 = *(const uint4*)&xls[(n * 16 + l15) * XST + koff];
            const uint4 u1 = *(const uint4*)&xls[(n * 16 + l15) * XST + koff + 4];
            unpack8(u0, u1, bh[n], bl[n]);
        }
        #pragma unroll
        for (int i = 0; i < 3; ++i)
            #pragma unroll
            for (int n = 0; n < 2; ++n) {
                acc[i][n] = __builtin_amdgcn_mfma_f32_16x16x32_bf16(cah[i], bh[n], acc[i][n], 0, 0, 0);
                acc[i][n] = __builtin_amdgcn_mfma_f32_16x16x32_bf16(cah[i], bl[n], acc[i][n], 0, 0, 0);
                acc[i][n] = __builtin_amdgcn_mfma_f32_16x16x32_bf16(cal[i], bh[n], acc[i][n], 0, 0, 0);
            }
        if (kc + 1 < SSKC) {
            #pragma unroll
            for (int i = 0; i < 3; ++i) { cah[i] = nah[i]; cal[i] = nal[i]; }
        }
    }

    // epilogue: rows <325 -> y1 (sect F); rows 336..660 -> y2 (sect 2F)
    #pragma unroll
    for (int i = 0; i < 3; ++i) {
        const int t = tb + i;
        #pragma unroll
        for (int n = 0; n < 2; ++n) {
            const int col = c0 + n * 16 + l15;
            if (col >= F) continue;
            #pragma unroll
            for (int r = 0; r < 4; ++r) {
                const int m = t * 16 + quad * 4 + r;
                if (m < N)
                    zcat[(size_t)(b * N + m) * K3P + F + col] = pack_hilo(acc[i][n][r]);
                else if (m >= 336 && m < 336 + N)
                    zcat[(size_t)(b * N + (m - 336)) * K3P + 2 * F + col] = pack_hilo(acc[i][n][r]);
            }
        }
    }
}

// ---------------- dense GEMM bodies (round-5 proven) ----------------

// Gate: ru = sigmoid(z @ Wg + b). nb = col-tile base (0 or 4), 4 tiles/block.
__device__ __forceinline__ void gate_body(const unsigned* __restrict__ zcat,
    int K3p, const short8* __restrict__ Wh, const short8* __restrict__ Wl,
    const float* __restrict__ bias, float* __restrict__ ru, int bx, int nb)
{
    constexpr int NT = 4;
    const int tid = threadIdx.x, wave = tid >> 6, lane = tid & 63;
    const int quad = lane >> 4, l15 = lane & 15;
    const int row0 = bx * 64 + wave * 16;

    floatx4 acc[NT];
    #pragma unroll
    for (int n = 0; n < NT; ++n) {
        const float bv = bias[(nb + n) * 16 + l15];
        acc[n] = (floatx4){bv, bv, bv, bv};
    }
    const unsigned* __restrict__ zrow = zcat + (size_t)(row0 + l15) * K3p + quad * 8;
    const int KC = K3p >> 5;
    for (int kc = 0; kc < KC; ++kc) {
        const uint4* p = (const uint4*)(zrow + kc * 32);
        short8 ahi, alo;
        unpack8(p[0], p[1], ahi, alo);
        const short8* __restrict__ wh = Wh + (size_t)(kc * 8 + nb) * 64 + lane;
        const short8* __restrict__ wl = Wl + (size_t)(kc * 8 + nb) * 64 + lane;
        #pragma unroll
        for (int n = 0; n < NT; ++n) {
            const short8 bh = wh[n * 64], bl = wl[n * 64];
            acc[n] = __builtin_amdgcn_mfma_f32_16x16x32_bf16(ahi, bh, acc[n], 0, 0, 0);
            acc[n] = __builtin_amdgcn_mfma_f32_16x16x32_bf16(ahi, bl, acc[n], 0, 0, 0);
            acc[n] = __builtin_amdgcn_mfma_f32_16x16x32_bf16(alo, bh, acc[n], 0, 0, 0);
        }
    }
    #pragma unroll
    for (int n = 0; n < NT; ++n) {
        const int col = (nb + n) * 16 + l15;
        #pragma unroll
        for (int r = 0; r < 4; ++r) {
            const int row = row0 + quad * 4 + r;
            ru[(size_t)row * 128 + col] = 1.f / (1.f + __expf(-acc[n][r]));
        }
    }
}

// Candidate (non-proj): c = tanh(z@W+b); h = u*h + (1-u)*c. nb = 0 or 2.
__device__ __forceinline__ void cand_body(const unsigned* __restrict__ zcat,
    int K3p, const short8* __restrict__ Wh, const short8* __restrict__ Wl,
    const float* __restrict__ bias, const float* __restrict__ ru,
    float* __restrict__ h, int bx, int nb)
{
    constexpr int NT = 2;
    const int tid = threadIdx.x, wave = tid >> 6, lane = tid & 63;
    const int quad = lane >> 4, l15 = lane & 15;
    const int row0 = bx * 64 + wave * 16;

    floatx4 acc[NT];
    #pragma unroll
    for (int n = 0; n < NT; ++n) {
        const float bv = bias[(nb + n) * 16 + l15];
        acc[n] = (floatx4){bv, bv, bv, bv};
    }
    const unsigned* __restrict__ zrow = zcat + (size_t)(row0 + l15) * K3p + quad * 8;
    const int KC = K3p >> 5;
    for (int kc = 0; kc < KC; ++kc) {
        const uint4* p = (const uint4*)(zrow + kc * 32);
        short8 ahi, alo;
        unpack8(p[0], p[1], ahi, alo);
        const short8* __restrict__ wh = Wh + (size_t)(kc * 4 + nb) * 64 + lane;
        const short8* __restrict__ wl = Wl + (size_t)(kc * 4 + nb) * 64 + lane;
        #pragma unroll
        for (int n = 0; n < NT; ++n) {
            const short8 bh = wh[n * 64], bl = wl[n * 64];
            acc[n] = __builtin_amdgcn_mfma_f32_16x16x32_bf16(ahi, bh, acc[n], 0, 0, 0);
            acc[n] = __builtin_amdgcn_mfma_f32_16x16x32_bf16(ahi, bl, acc[n], 0, 0, 0);
            acc[n] = __builtin_amdgcn_mfma_f32_16x16x32_bf16(alo, bh, acc[n], 0, 0, 0);
        }
    }
    #pragma unroll
    for (int n = 0; n < NT; ++n) {
        const int col = (nb + n) * 16 + l15;
        #pragma unroll
        for (int r = 0; r < 4; ++r) {
            const int row = row0 + quad * 4 + r;
            const float c  = tanhf(acc[n][r]);
            const float ug = ru[(size_t)row * 128 + 64 + col];  // u = ru[:,64:]
            const float hv = h[(size_t)row * 64 + col];
            h[(size_t)row * 64 + col] = ug * hv + (1.f - ug) * c;
        }
    }
}

// ---------------- solo kernels ----------------

template<int DIN, int F, int K3P, bool RMUL, int CB>
__global__ __launch_bounds__(448, 3)
void diffuse_solo(const short8* __restrict__ ssh, const short8* __restrict__ ssl,
                  const float* __restrict__ x, const float* __restrict__ h,
                  const float* __restrict__ ru, unsigned* __restrict__ zcat)
{
    __shared__ __align__(16) unsigned xls[32 * XST];
    diffuse_body<DIN, F, K3P, RMUL>(ssh, ssl, x, h, ru, zcat,
                                    CB + blockIdx.x, blockIdx.y, blockIdx.z, xls);
}

__global__ __launch_bounds__(256)
void gate_solo(const unsigned* __restrict__ zcat, int K3p,
               const short8* __restrict__ Wh, const short8* __restrict__ Wl,
               const float* __restrict__ bias, float* __restrict__ ru)
{
    gate_body(zcat, K3p, Wh, Wl, bias, ru, blockIdx.x, blockIdx.y * 4);
}

__global__ __launch_bounds__(256)
void cand_solo(const unsigned* __restrict__ zcat, int K3p,
               const short8* __restrict__ Wh, const short8* __restrict__ Wl,
               const float* __restrict__ bias, const float* __restrict__ ru,
               float* __restrict__ h)
{
    cand_body(zcat, K3p, Wh, Wl, bias, ru, h, blockIdx.x, blockIdx.y * 2);
}

// Candidate + fused projection (decoder layer 1). NT=4, unsplit.
__global__ __launch_bounds__(256)
void cand_proj(const unsigned* __restrict__ zcat, int K3p,
               const short8* __restrict__ Wh, const short8* __restrict__ Wl,
               const float* __restrict__ bias, const float* __restrict__ ru,
               float* __restrict__ h, const float* __restrict__ pW,
               const float* __restrict__ pb, float* __restrict__ outp,
               float* __restrict__ dec_in)
{
    constexpr int NT = 4;
    const int tid = threadIdx.x, wave = tid >> 6, lane = tid & 63;
    const int quad = lane >> 4, l15 = lane & 15;
    const int row0 = blockIdx.x * 64 + wave * 16;

    floatx4 acc[NT];
    #pragma unroll
    for (int n = 0; n < NT; ++n) {
        const float bv = bias[n * 16 + l15];
        acc[n] = (floatx4){bv, bv, bv, bv};
    }
    const unsigned* __restrict__ zrow = zcat + (size_t)(row0 + l15) * K3p + quad * 8;
    const int KC = K3p >> 5;
    for (int kc = 0; kc < KC; ++kc) {
        const uint4* p = (const uint4*)(zrow + kc * 32);
        short8 ahi, alo;
        unpack8(p[0], p[1], ahi, alo);
        const short8* __restrict__ wh = Wh + (size_t)(kc * 4) * 64 + lane;
        const short8* __restrict__ wl = Wl + (size_t)(kc * 4) * 64 + lane;
        #pragma unroll
        for (int n = 0; n < NT; ++n) {
            const short8 bh = wh[n * 64], bl = wl[n * 64];
            acc[n] = __builtin_amdgcn_mfma_f32_16x16x32_bf16(ahi, bh, acc[n], 0, 0, 0);
            acc[n] = __builtin_amdgcn_mfma_f32_16x16x32_bf16(ahi, bl, acc[n], 0, 0, 0);
            acc[n] = __builtin_amdgcn_mfma_f32_16x16x32_bf16(alo, bh, acc[n], 0, 0, 0);
        }
    }
    float pr[4] = {0.f, 0.f, 0.f, 0.f};
    #pragma unroll
    for (int n = 0; n < NT; ++n) {
        const int col = n * 16 + l15;
        const float pw = pW[col];
        #pragma unroll
        for (int r = 0; r < 4; ++r) {
            const int row = row0 + quad * 4 + r;
            const float c  = tanhf(acc[n][r]);
            const float ug = ru[(size_t)row * 128 + 64 + col];
            const float hv = h[(size_t)row * 64 + col];
            const float hn = ug * hv + (1.f - ug) * c;
            h[(size_t)row * 64 + col] = hn;
            pr[r] += hn * pw;
        }
    }
    #pragma unroll
    for (int r = 0; r < 4; ++r) {
        float v = pr[r];
        v += __shfl_xor(v, 1); v += __shfl_xor(v, 2);
        v += __shfl_xor(v, 4); v += __shfl_xor(v, 8);
        if (l15 == 0) {
            const int row = row0 + quad * 4 + r;
            const float o = v + pb[0];
            outp[row]   = o;
            dec_in[row] = o;
        }
    }
}

// ---------------- duo kernels (encoder pipelining) ----------------
// Cell A = encoder layer0 step t (DIN=2,F=66,K3P=224),
// Cell B = encoder layer1 step t-1 (DIN=64,F=128,K3P=384). Independent work,
// one dispatch. blockIdx.z: 0,1 -> cellA M-half; 2,3 -> cellB M-half.

struct DuoDP {
    const short8 *ssh, *ssl;
    const float *xA, *hA, *ruA; unsigned* zA;
    const float *xB, *hB, *ruB; unsigned* zB;
    int cbB;   // cell B chunk base (0 for gate pass, 2 for cand pass: h-cols only)
};

template<bool RM>
__global__ __launch_bounds__(448, 3)
void diffuse_duo(DuoDP P)
{
    __shared__ __align__(16) unsigned xls[32 * XST];
    const int zz = blockIdx.z;
    if (zz < 2) {
        if ((int)blockIdx.x < 3)
            diffuse_body<2, 66, 224, RM>(P.ssh, P.ssl, P.xA, P.hA, P.ruA, P.zA,
                                         blockIdx.x, blockIdx.y, zz, xls);
    } else {
        if ((int)blockIdx.x < 4 - P.cbB)
            diffuse_body<64, 128, 384, RM>(P.ssh, P.ssl, P.xB, P.hB, P.ruB, P.zB,
                                           P.cbB + blockIdx.x, blockIdx.y, zz - 2, xls);
    }
}

struct DuoGP {
    const unsigned* zA; const short8 *WhA, *WlA; const float* bA; float* ruA;
    const unsigned* zB; const short8 *WhB, *WlB; const float* bB; float* ruB;
};

__global__ __launch_bounds__(256)
void gate_duo(DuoGP P)
{
    if (blockIdx.z == 0)
        gate_body(P.zA, 224, P.WhA, P.WlA, P.bA, P.ruA, blockIdx.x, blockIdx.y * 4);
    else
        gate_body(P.zB, 384, P.WhB, P.WlB, P.bB, P.ruB, blockIdx.x, blockIdx.y * 4);
}

struct DuoCP {
    const unsigned* zA; const short8 *WhA, *WlA; const float* bA;
    const float* ruA; float* hA;
    const unsigned* zB; const short8 *WhB, *WlB; const float* bB;
    const float* ruB; float* hB;
};

__global__ __launch_bounds__(256)
void cand_duo(DuoCP P)
{
    if (blockIdx.z == 0)
        cand_body(P.zA, 224, P.WhA, P.WlA, P.bA, P.ruA, P.hA, blockIdx.x, blockIdx.y * 2);
    else
        cand_body(P.zB, 384, P.WhB, P.WlB, P.bB, P.ruB, P.hB, blockIdx.x, blockIdx.y * 2);
}

// ---------------- host launcher ----------------

extern "C" void kernel_launch(void* const* d_in, const int* in_sizes, int n_in,
                              void* d_out, int out_size, void* d_ws, size_t ws_size,
                              hipStream_t stream)
{
    const float* inputs = (const float*)d_in[0];
    const float* S      = (const float*)d_in[1];
    const float* Wt[4][4];
    for (int l = 0; l < 4; ++l)
        for (int j = 0; j < 4; ++j)
            Wt[l][j] = (const float*)d_in[2 + l * 4 + j];
    const float* pW = (const float*)d_in[18];
    const float* pb = (const float*)d_in[19];
    float* out = (float*)d_out;

    // workspace layout
    float*    ws     = (float*)d_ws;
    float*    h0     = ws;                         // BN*64
    float*    h1     = h0 + (size_t)BN * U;        // BN*64
    float*    dec_in = h1 + (size_t)BN * U;        // BN
    float*    ruA    = dec_in + BN;                // BN*128
    float*    ruB    = ruA + (size_t)BN * 128;     // BN*128
    unsigned* zcatA  = (unsigned*)(ruB + (size_t)BN * 128);  // BN*224
    unsigned* zcatB  = zcatA + (size_t)BN * 224;             // BN*384
    float*    S2     = (float*)(zcatB + (size_t)BN * 384);   // N*N
    char*     pp     = (char*)(S2 + (size_t)N * N);
    pp = (char*)(((uintptr_t)pp + 15) & ~(uintptr_t)15);

    short* ssh = (short*)pp;                       // 42*11*64*8 shorts
    short* ssl = ssh + (size_t)SSTIL * SSKC * 64 * 8;
    char*  wpbase = (char*)(ssl + (size_t)SSTIL * SSKC * 64 * 8);

    const int Fs[4]   = {66, 128, 65, 128};
    const int K3ps[4] = {224, 384, 224, 384};
    short *Wgh[4], *Wgl[4], *Wch[4], *Wcl[4];
    size_t off = 0;
    for (int l = 0; l < 4; ++l) {
        const size_t ge = (size_t)K3ps[l] * 128, ce = (size_t)K3ps[l] * 64;
        Wgh[l] = (short*)(wpbase + off); off += ge * 2;
        Wgl[l] = (short*)(wpbase + off); off += ge * 2;
        Wch[l] = (short*)(wpbase + off); off += ce * 2;
        Wcl[l] = (short*)(wpbase + off); off += ce * 2;
    }

    // zero state + both zcat buffers (pad strips must start benign; per replay)
    const long zn = (long)BN * (2 * U) + BN + (long)BN * 256 + (long)BN * (224 + 384);
    zero_kernel<<<2048, 256, 0, stream>>>((unsigned*)h0, zn);

    s2_build<<<N, 256, 0, stream>>>(S, S2);
    prepack_ss<<<dim3(SSTIL, SSKC), 64, 0, stream>>>(S, S2, ssh, ssl);
    for (int l = 0; l < 4; ++l) {
        prepack_w<<<dim3(K3ps[l] / 32, 8), 64, 0, stream>>>(Wt[l][0], Wgh[l], Wgl[l],
                                                            Fs[l], 128, 8);
        prepack_w<<<dim3(K3ps[l] / 32, 4), 64, 0, stream>>>(Wt[l][2], Wch[l], Wcl[l],
                                                            Fs[l], 64, 4);
    }

    const short8* SSH = (const short8*)ssh;
    const short8* SSL = (const short8*)ssl;

    // -------- encoder: software-pipelined (cell0 step s || cell1 step s-1) ----
    for (int s = 0; s <= T; ++s) {
        const float* x0 = inputs + (size_t)s * BN * 2;
        const bool a = (s < T), b1 = (s >= 1);
        if (a && b1) {
            DuoDP dp{SSH, SSL, x0, h0, nullptr, zcatA, h0, h1, nullptr, zcatB, 0};
            diffuse_duo<false><<<dim3(4, B, 4), 448, 0, stream>>>(dp);
            DuoGP gp{zcatA, (short8*)Wgh[0], (short8*)Wgl[0], Wt[0][1], ruA,
                     zcatB, (short8*)Wgh[1], (short8*)Wgl[1], Wt[1][1], ruB};
            gate_duo<<<dim3(BN / 64, 2, 2), 256, 0, stream>>>(gp);
            DuoDP dp2{SSH, SSL, x0, h0, ruA, zcatA, h0, h1, ruB, zcatB, 2};
            diffuse_duo<true><<<dim3(3, B, 4), 448, 0, stream>>>(dp2);
            DuoCP cp{zcatA, (short8*)Wch[0], (short8*)Wcl[0], Wt[0][3], ruA, h0,
                     zcatB, (short8*)Wch[1], (short8*)Wcl[1], Wt[1][3], ruB, h1};
            cand_duo<<<dim3(BN / 64, 2, 2), 256, 0, stream>>>(cp);
        } else if (a) {  // s == 0: cell0 solo
            diffuse_solo<2, 66, 224, false, 0><<<dim3(3, B, 2), 448, 0, stream>>>(
                SSH, SSL, x0, h0, nullptr, zcatA);
            gate_solo<<<dim3(BN / 64, 2), 256, 0, stream>>>(
                zcatA, 224, (short8*)Wgh[0], (short8*)Wgl[0], Wt[0][1], ruA);
            diffuse_solo<2, 66, 224, true, 0><<<dim3(3, B, 2), 448, 0, stream>>>(
                SSH, SSL, x0, h0, ruA, zcatA);
            cand_solo<<<dim3(BN / 64, 2), 256, 0, stream>>>(
                zcatA, 224, (short8*)Wch[0], (short8*)Wcl[0], Wt[0][3], ruA, h0);
        } else {         // s == T: cell1 drain
            diffuse_solo<64, 128, 384, false, 0><<<dim3(4, B, 2), 448, 0, stream>>>(
                SSH, SSL, h0, h1, nullptr, zcatB);
            gate_solo<<<dim3(BN / 64, 2), 256, 0, stream>>>(
                zcatB, 384, (short8*)Wgh[1], (short8*)Wgl[1], Wt[1][1], ruB);
            diffuse_solo<64, 128, 384, true, 2><<<dim3(2, B, 2), 448, 0, stream>>>(
                SSH, SSL, h0, h1, ruB, zcatB);
            cand_solo<<<dim3(BN / 64, 2), 256, 0, stream>>>(
                zcatB, 384, (short8*)Wch[1], (short8*)Wcl[1], Wt[1][3], ruB, h1);
        }
    }

    // -------- decoder (sequential; D2 layer-1 computes h-cols only) --------
    for (int hz = 0; hz < HZ; ++hz) {
        diffuse_solo<1, 65, 224, false, 0><<<dim3(3, B, 2), 448, 0, stream>>>(
            SSH, SSL, dec_in, h0, nullptr, zcatB);
        gate_solo<<<dim3(BN / 64, 2), 256, 0, stream>>>(
            zcatB, 224, (short8*)Wgh[2], (short8*)Wgl[2], Wt[2][1], ruA);
        diffuse_solo<1, 65, 224, true, 0><<<dim3(3, B, 2), 448, 0, stream>>>(
            SSH, SSL, dec_in, h0, ruA, zcatB);
        cand_solo<<<dim3(BN / 64, 2), 256, 0, stream>>>(
            zcatB, 224, (short8*)Wch[2], (short8*)Wcl[2], Wt[2][3], ruA, h0);
        diffuse_solo<64, 128, 384, false, 0><<<dim3(4, B, 2), 448, 0, stream>>>(
            SSH, SSL, h0, h1, nullptr, zcatB);
        gate_solo<<<dim3(BN / 64, 2), 256, 0, stream>>>(
            zcatB, 384, (short8*)Wgh[3], (short8*)Wgl[3], Wt[3][1], ruA);
        diffuse_solo<64, 128, 384, true, 2><<<dim3(2, B, 2), 448, 0, stream>>>(
            SSH, SSL, h0, h1, ruA, zcatB);
        cand_proj<<<BN / 64, 256, 0, stream>>>(
            zcatB, 384, (short8*)Wch[3], (short8*)Wcl[3], Wt[3][3], ruA, h1,
            pW, pb, out + (size_t)hz * BN, dec_in);
    }
}

// Round 9
// 4080.339 us; speedup vs baseline: 2.6967x; 1.0004x over previous
//
#include <hip/hip_runtime.h>

// ---------------- problem constants ----------------
constexpr int N  = 325;   // nodes
constexpr int B  = 64;    // batch
constexpr int T  = 12;    // encoder steps
constexpr int HZ = 12;    // decoder horizon
constexpr int U  = 64;    // rnn units
constexpr int BN = B * N; // 20800 rows

// SS = [S ; S^2] stacked: rows [0,325)=S, [336,661)=S^2 (42 tiles of 16)
constexpr int SSTIL = 42;
constexpr int SSKC  = 11;   // K chunks of 32 (K padded 325->352)
constexpr int XST   = 364;  // u32 stride per feature column in diffuse LDS

typedef __attribute__((ext_vector_type(8))) short short8;
typedef __attribute__((ext_vector_type(4))) float floatx4;

// bf16 round-to-nearest-even + hi/lo split helpers
__device__ inline unsigned short f2bf(float f) {
    unsigned u = __float_as_uint(f);
    u += 0x7fff + ((u >> 16) & 1);
    return (unsigned short)(u >> 16);
}
__device__ inline unsigned pack_hilo(float v) {
    const unsigned short hi = f2bf(v);
    const float hif = __uint_as_float(((unsigned)hi) << 16);
    const unsigned short lo = f2bf(v - hif);
    return (unsigned)hi | ((unsigned)lo << 16);
}
__device__ inline void unpack8(const uint4 u0, const uint4 u1,
                               short8& h, short8& l) {
    const unsigned uu[8] = {u0.x, u0.y, u0.z, u0.w, u1.x, u1.y, u1.z, u1.w};
    #pragma unroll
    for (int j = 0; j < 8; ++j) {
        h[j] = (short)(uu[j] & 0xffffu);
        l[j] = (short)(uu[j] >> 16);
    }
}

// ---------------- setup kernels ----------------

__global__ void zero_kernel(unsigned* __restrict__ p, long n) {
    long i = (long)blockIdx.x * blockDim.x + threadIdx.x;
    const long stride = (long)gridDim.x * blockDim.x;
    for (; i < n; i += stride) p[i] = 0u;
}

// S2 = S @ S (fp32). One block per output row.
__global__ __launch_bounds__(256)
void s2_build(const float* __restrict__ S, float* __restrict__ S2)
{
    const int m = blockIdx.x;
    __shared__ float srow[N];
    for (int i = threadIdx.x; i < N; i += 256) srow[i] = S[m * N + i];
    __syncthreads();
    for (int c = threadIdx.x; c < N; c += 256) {
        float a = 0.f;
        for (int k = 0; k < N; ++k) a += srow[k] * S[k * N + c];
        S2[m * N + c] = a;
    }
}

// Prepack SS=[S;S2] into MFMA A-fragments (bf16 hi/lo).
// A-frag: lane l holds A[row = t*16 + (l&15)][k = kc*32 + (l>>4)*8 + j].
__global__ __launch_bounds__(64)
void prepack_ss(const float* __restrict__ S, const float* __restrict__ S2,
                short* __restrict__ ssh, short* __restrict__ ssl)
{
    const int t = blockIdx.x, kc = blockIdx.y, lane = threadIdx.x;
    const int quad = lane >> 4, l15 = lane & 15;
    short8 hv, lv;
    #pragma unroll
    for (int j = 0; j < 8; ++j) {
        const int m = t * 16 + l15;
        const int k = kc * 32 + quad * 8 + j;
        float v = 0.f;
        if (k < N) {
            if (m < N) v = S[m * N + k];
            else if (m >= 336 && m < 336 + N) v = S2[(m - 336) * N + k];
        }
        const unsigned short hb = f2bf(v);
        hv[j] = (short)hb;
        lv[j] = (short)f2bf(v - __uint_as_float(((unsigned)hb) << 16));
    }
    const size_t off = ((size_t)(t * SSKC + kc) * 64 + lane);
    ((short8*)ssh)[off] = hv;
    ((short8*)ssl)[off] = lv;
}

// Prepack weights (3F x Nout fp32, level-major) into MFMA B-fragment order,
// bf16 hi/lo, K padded to K3P, Chebyshev fold: W0'=W0-W2, W1'=W1, W2'=2*W2.
__global__ __launch_bounds__(64)
void prepack_w(const float* __restrict__ W, short* __restrict__ Wh,
               short* __restrict__ Wl, int F, int Nout, int NT)
{
    const int kc = blockIdx.x, n = blockIdx.y, lane = threadIdx.x;
    const int quad = lane >> 4, l15 = lane & 15;
    short8 hv, lv;
    #pragma unroll
    for (int j = 0; j < 8; ++j) {
        const int k   = kc * 32 + quad * 8 + j;
        const int col = n * 16 + l15;
        const int lvl = k / F, f = k - lvl * F;
        float w = 0.f;
        if (lvl == 0)
            w = W[(size_t)f * Nout + col] - W[(size_t)(2 * F + f) * Nout + col];
        else if (lvl == 1)
            w = W[(size_t)(F + f) * Nout + col];
        else if (lvl == 2)
            w = 2.f * W[(size_t)(2 * F + f) * Nout + col];
        const unsigned short hb = f2bf(w);
        hv[j] = (short)hb;
        lv[j] = (short)f2bf(w - __uint_as_float(((unsigned)hb) << 16));
    }
    const size_t off = ((size_t)(kc * NT + n) * 64 + lane);
    ((short8*)Wh)[off] = hv;
    ((short8*)Wl)[off] = lv;
}

// ---------------- diffusion GEMM body (merged M-halves, 896 thr) ----------------
// Y = SS @ X_b for one (batch, 32-col feature chunk cx). X staged ONCE per
// block; 14 waves x 3 row tiles = all 42 tiles. Writes packed
// z = [z0 | y1 | y2] sections of zcat. VEC path for DIN=64 (chunk uniformly
// x- or h-part, 16B-aligned): float4 reads, uint4 z0 stores.
template<int DIN, int F, int K3P, bool RMUL, bool VEC>
__device__ __forceinline__ void diffuse_body(
    const short8* __restrict__ ssh, const short8* __restrict__ ssl,
    const float* __restrict__ x, const float* __restrict__ h,
    const float* __restrict__ ru, unsigned* __restrict__ zcat,
    int cx, int b, unsigned* __restrict__ xls)
{
    const int c0 = cx * 32;
    const int tid = threadIdx.x, wave = tid >> 6, lane = tid & 63;
    const int quad = lane >> 4, l15 = lane & 15;

    if constexpr (VEC) {
        for (int idx4 = tid; idx4 < 352 * 8; idx4 += 896) {
            const int n = idx4 >> 3, f = (idx4 & 7) * 4, gf = c0 + f;
            uint4 pk = make_uint4(0u, 0u, 0u, 0u);
            if (n < N) {
                const int row = b * N + n;
                float4 v;
                if (gf < DIN) {
                    v = *(const float4*)&x[(size_t)row * DIN + gf];
                } else {
                    v = *(const float4*)&h[(size_t)row * U + (gf - DIN)];
                    if (RMUL) {
                        const float4 rv = *(const float4*)&ru[(size_t)row * 128 + (gf - DIN)];
                        v.x *= rv.x; v.y *= rv.y; v.z *= rv.z; v.w *= rv.w;
                    }
                }
                pk.x = pack_hilo(v.x); pk.y = pack_hilo(v.y);
                pk.z = pack_hilo(v.z); pk.w = pack_hilo(v.w);
                if (!(RMUL && gf < DIN))   // x-part identical to gate pass
                    *(uint4*)&zcat[(size_t)row * K3P + gf] = pk;
            }
            xls[(f + 0) * XST + n] = pk.x;
            xls[(f + 1) * XST + n] = pk.y;
            xls[(f + 2) * XST + n] = pk.z;
            xls[(f + 3) * XST + n] = pk.w;
        }
    } else {
        for (int idx = tid; idx < 352 * 32; idx += 896) {
            const int n = idx >> 5, f = idx & 31, gf = c0 + f;
            unsigned u = 0u;
            if (n < N && gf < F) {
                const int row = b * N + n;
                float v;
                if (gf < DIN) {
                    v = x[(size_t)row * DIN + gf];
                } else {
                    v = h[(size_t)row * U + (gf - DIN)];
                    if (RMUL) v *= ru[(size_t)row * 128 + (gf - DIN)];  // r = ru[:,:64]
                }
                u = pack_hilo(v);
                if (!(RMUL && gf < DIN))
                    zcat[(size_t)row * K3P + gf] = u;
            }
            xls[f * XST + n] = u;
        }
    }
    __syncthreads();

    const int tb = wave * 3;  // 3 row tiles per wave, 14 waves -> 42 tiles

    floatx4 acc[3][2];
    #pragma unroll
    for (int i = 0; i < 3; ++i)
        #pragma unroll
        for (int n = 0; n < 2; ++n)
            acc[i][n] = (floatx4){0.f, 0.f, 0.f, 0.f};

    // A-fragment double buffer: prefetch kc+1 while MFMAing kc
    short8 cah[3], cal[3], nah[3], nal[3];
    #pragma unroll
    for (int i = 0; i < 3; ++i) {
        const size_t fo = (size_t)((tb + i) * SSKC) * 64 + lane;
        cah[i] = ssh[fo]; cal[i] = ssl[fo];
    }
    for (int kc = 0; kc < SSKC; ++kc) {
        if (kc + 1 < SSKC) {
            #pragma unroll
            for (int i = 0; i < 3; ++i) {
                const size_t fo = (size_t)((tb + i) * SSKC + kc + 1) * 64 + lane;
                nah[i] = ssh[fo]; nal[i] = ssl[fo];
            }
        }
        short8 bh[2], bl[2];
        const int koff = kc * 32 + quad * 8;
        #pragma unroll
        for (int n = 0; n < 2; ++n) {
            const uint4 u0 = *(const uint4*)&xls[(n * 16 + l15) * XST + koff];
            const uint4 u1 = *(const uint4*)&xls[(n * 16 + l15) * XST + koff + 4];
            unpack8(u0, u1, bh[n], bl[n]);
        }
        #pragma unroll
        for (int i = 0; i < 3; ++i)
            #pragma unroll
            for (int n = 0; n < 2; ++n) {
                acc[i][n] = __builtin_amdgcn_mfma_f32_16x16x32_bf16(cah[i], bh[n], acc[i][n], 0, 0, 0);
                acc[i][n] = __builtin_amdgcn_mfma_f32_16x16x32_bf16(cah[i], bl[n], acc[i][n], 0, 0, 0);
                acc[i][n] = __builtin_amdgcn_mfma_f32_16x16x32_bf16(cal[i], bh[n], acc[i][n], 0, 0, 0);
            }
        if (kc + 1 < SSKC) {
            #pragma unroll
            for (int i = 0; i < 3; ++i) { cah[i] = nah[i]; cal[i] = nal[i]; }
        }
    }

    // epilogue: rows <325 -> y1 (sect F); rows 336..660 -> y2 (sect 2F)
    #pragma unroll
    for (int i = 0; i < 3; ++i) {
        const int t = tb + i;
        #pragma unroll
        for (int n = 0; n < 2; ++n) {
            const int col = c0 + n * 16 + l15;
            if (col >= F) continue;
            #pragma unroll
            for (int r = 0; r < 4; ++r) {
                const int m = t * 16 + quad * 4 + r;
                if (m < N)
                    zcat[(size_t)(b * N + m) * K3P + F + col] = pack_hilo(acc[i][n][r]);
                else if (m >= 336 && m < 336 + N)
                    zcat[(size_t)(b * N + (m - 336)) * K3P + 2 * F + col] = pack_hilo(acc[i][n][r]);
            }
        }
    }
}

// ---------------- dense GEMM bodies (proven) ----------------

// Gate: ru = sigmoid(z @ Wg + b). nb = col-tile base (0 or 4), 4 tiles/block.
__device__ __forceinline__ void gate_body(const unsigned* __restrict__ zcat,
    int K3p, const short8* __restrict__ Wh, const short8* __restrict__ Wl,
    const float* __restrict__ bias, float* __restrict__ ru, int bx, int nb)
{
    constexpr int NT = 4;
    const int tid = threadIdx.x, wave = tid >> 6, lane = tid & 63;
    const int quad = lane >> 4, l15 = lane & 15;
    const int row0 = bx * 64 + wave * 16;

    floatx4 acc[NT];
    #pragma unroll
    for (int n = 0; n < NT; ++n) {
        const float bv = bias[(nb + n) * 16 + l15];
        acc[n] = (floatx4){bv, bv, bv, bv};
    }
    const unsigned* __restrict__ zrow = zcat + (size_t)(row0 + l15) * K3p + quad * 8;
    const int KC = K3p >> 5;
    for (int kc = 0; kc < KC; ++kc) {
        const uint4* p = (const uint4*)(zrow + kc * 32);
        short8 ahi, alo;
        unpack8(p[0], p[1], ahi, alo);
        const short8* __restrict__ wh = Wh + (size_t)(kc * 8 + nb) * 64 + lane;
        const short8* __restrict__ wl = Wl + (size_t)(kc * 8 + nb) * 64 + lane;
        #pragma unroll
        for (int n = 0; n < NT; ++n) {
            const short8 bh = wh[n * 64], bl = wl[n * 64];
            acc[n] = __builtin_amdgcn_mfma_f32_16x16x32_bf16(ahi, bh, acc[n], 0, 0, 0);
            acc[n] = __builtin_amdgcn_mfma_f32_16x16x32_bf16(ahi, bl, acc[n], 0, 0, 0);
            acc[n] = __builtin_amdgcn_mfma_f32_16x16x32_bf16(alo, bh, acc[n], 0, 0, 0);
        }
    }
    #pragma unroll
    for (int n = 0; n < NT; ++n) {
        const int col = (nb + n) * 16 + l15;
        #pragma unroll
        for (int r = 0; r < 4; ++r) {
            const int row = row0 + quad * 4 + r;
            ru[(size_t)row * 128 + col] = 1.f / (1.f + __expf(-acc[n][r]));
        }
    }
}

// Candidate (non-proj): c = tanh(z@W+b); h = u*h + (1-u)*c. nb = 0 or 2.
__device__ __forceinline__ void cand_body(const unsigned* __restrict__ zcat,
    int K3p, const short8* __restrict__ Wh, const short8* __restrict__ Wl,
    const float* __restrict__ bias, const float* __restrict__ ru,
    float* __restrict__ h, int bx, int nb)
{
    constexpr int NT = 2;
    const int tid = threadIdx.x, wave = tid >> 6, lane = tid & 63;
    const int quad = lane >> 4, l15 = lane & 15;
    const int row0 = bx * 64 + wave * 16;

    floatx4 acc[NT];
    #pragma unroll
    for (int n = 0; n < NT; ++n) {
        const float bv = bias[(nb + n) * 16 + l15];
        acc[n] = (floatx4){bv, bv, bv, bv};
    }
    const unsigned* __restrict__ zrow = zcat + (size_t)(row0 + l15) * K3p + quad * 8;
    const int KC = K3p >> 5;
    for (int kc = 0; kc < KC; ++kc) {
        const uint4* p = (const uint4*)(zrow + kc * 32);
        short8 ahi, alo;
        unpack8(p[0], p[1], ahi, alo);
        const short8* __restrict__ wh = Wh + (size_t)(kc * 4 + nb) * 64 + lane;
        const short8* __restrict__ wl = Wl + (size_t)(kc * 4 + nb) * 64 + lane;
        #pragma unroll
        for (int n = 0; n < NT; ++n) {
            const short8 bh = wh[n * 64], bl = wl[n * 64];
            acc[n] = __builtin_amdgcn_mfma_f32_16x16x32_bf16(ahi, bh, acc[n], 0, 0, 0);
            acc[n] = __builtin_amdgcn_mfma_f32_16x16x32_bf16(ahi, bl, acc[n], 0, 0, 0);
            acc[n] = __builtin_amdgcn_mfma_f32_16x16x32_bf16(alo, bh, acc[n], 0, 0, 0);
        }
    }
    #pragma unroll
    for (int n = 0; n < NT; ++n) {
        const int col = (nb + n) * 16 + l15;
        #pragma unroll
        for (int r = 0; r < 4; ++r) {
            const int row = row0 + quad * 4 + r;
            const float c  = tanhf(acc[n][r]);
            const float ug = ru[(size_t)row * 128 + 64 + col];  // u = ru[:,64:]
            const float hv = h[(size_t)row * 64 + col];
            h[(size_t)row * 64 + col] = ug * hv + (1.f - ug) * c;
        }
    }
}

// ---------------- solo kernels ----------------

template<int DIN, int F, int K3P, bool RMUL, int CB, bool VEC>
__global__ __launch_bounds__(896, 7)
void diffuse_solo(const short8* __restrict__ ssh, const short8* __restrict__ ssl,
                  const float* __restrict__ x, const float* __restrict__ h,
                  const float* __restrict__ ru, unsigned* __restrict__ zcat)
{
    __shared__ __align__(16) unsigned xls[32 * XST];
    diffuse_body<DIN, F, K3P, RMUL, VEC>(ssh, ssl, x, h, ru, zcat,
                                         CB + blockIdx.x, blockIdx.y, xls);
}

__global__ __launch_bounds__(256)
void gate_solo(const unsigned* __restrict__ zcat, int K3p,
               const short8* __restrict__ Wh, const short8* __restrict__ Wl,
               const float* __restrict__ bias, float* __restrict__ ru)
{
    gate_body(zcat, K3p, Wh, Wl, bias, ru, blockIdx.x, blockIdx.y * 4);
}

__global__ __launch_bounds__(256)
void cand_solo(const unsigned* __restrict__ zcat, int K3p,
               const short8* __restrict__ Wh, const short8* __restrict__ Wl,
               const float* __restrict__ bias, const float* __restrict__ ru,
               float* __restrict__ h)
{
    cand_body(zcat, K3p, Wh, Wl, bias, ru, h, blockIdx.x, blockIdx.y * 2);
}

// Candidate + fused projection (decoder layer 1). NT=4, unsplit.
__global__ __launch_bounds__(256)
void cand_proj(const unsigned* __restrict__ zcat, int K3p,
               const short8* __restrict__ Wh, const short8* __restrict__ Wl,
               const float* __restrict__ bias, const float* __restrict__ ru,
               float* __restrict__ h, const float* __restrict__ pW,
               const float* __restrict__ pb, float* __restrict__ outp,
               float* __restrict__ dec_in)
{
    constexpr int NT = 4;
    const int tid = threadIdx.x, wave = tid >> 6, lane = tid & 63;
    const int quad = lane >> 4, l15 = lane & 15;
    const int row0 = blockIdx.x * 64 + wave * 16;

    floatx4 acc[NT];
    #pragma unroll
    for (int n = 0; n < NT; ++n) {
        const float bv = bias[n * 16 + l15];
        acc[n] = (floatx4){bv, bv, bv, bv};
    }
    const unsigned* __restrict__ zrow = zcat + (size_t)(row0 + l15) * K3p + quad * 8;
    const int KC = K3p >> 5;
    for (int kc = 0; kc < KC; ++kc) {
        const uint4* p = (const uint4*)(zrow + kc * 32);
        short8 ahi, alo;
        unpack8(p[0], p[1], ahi, alo);
        const short8* __restrict__ wh = Wh + (size_t)(kc * 4) * 64 + lane;
        const short8* __restrict__ wl = Wl + (size_t)(kc * 4) * 64 + lane;
        #pragma unroll
        for (int n = 0; n < NT; ++n) {
            const short8 bh = wh[n * 64], bl = wl[n * 64];
            acc[n] = __builtin_amdgcn_mfma_f32_16x16x32_bf16(ahi, bh, acc[n], 0, 0, 0);
            acc[n] = __builtin_amdgcn_mfma_f32_16x16x32_bf16(ahi, bl, acc[n], 0, 0, 0);
            acc[n] = __builtin_amdgcn_mfma_f32_16x16x32_bf16(alo, bh, acc[n], 0, 0, 0);
        }
    }
    float pr[4] = {0.f, 0.f, 0.f, 0.f};
    #pragma unroll
    for (int n = 0; n < NT; ++n) {
        const int col = n * 16 + l15;
        const float pw = pW[col];
        #pragma unroll
        for (int r = 0; r < 4; ++r) {
            const int row = row0 + quad * 4 + r;
            const float c  = tanhf(acc[n][r]);
            const float ug = ru[(size_t)row * 128 + 64 + col];
            const float hv = h[(size_t)row * 64 + col];
            const float hn = ug * hv + (1.f - ug) * c;
            h[(size_t)row * 64 + col] = hn;
            pr[r] += hn * pw;
        }
    }
    #pragma unroll
    for (int r = 0; r < 4; ++r) {
        float v = pr[r];
        v += __shfl_xor(v, 1); v += __shfl_xor(v, 2);
        v += __shfl_xor(v, 4); v += __shfl_xor(v, 8);
        if (l15 == 0) {
            const int row = row0 + quad * 4 + r;
            const float o = v + pb[0];
            outp[row]   = o;
            dec_in[row] = o;
        }
    }
}

// ---------------- duo kernels (encoder pipelining) ----------------
// Cell A = encoder layer0 step t (DIN=2,F=66,K3P=224),
// Cell B = encoder layer1 step t-1 (DIN=64,F=128,K3P=384). Independent work,
// one dispatch. blockIdx.x < cA -> cellA chunk; else cellB chunk cbB+...

struct DuoDP {
    const short8 *ssh, *ssl;
    const float *xA, *hA, *ruA; unsigned* zA;
    const float *xB, *hB, *ruB; unsigned* zB;
    int cA;    // cell A chunk count (3)
    int cbB;   // cell B chunk base (0 gate pass; 2 cand pass: h-cols only)
};

template<bool RM>
__global__ __launch_bounds__(896, 7)
void diffuse_duo(DuoDP P)
{
    __shared__ __align__(16) unsigned xls[32 * XST];
    if ((int)blockIdx.x < P.cA)
        diffuse_body<2, 66, 224, RM, false>(P.ssh, P.ssl, P.xA, P.hA, P.ruA,
                                            P.zA, blockIdx.x, blockIdx.y, xls);
    else
        diffuse_body<64, 128, 384, RM, true>(P.ssh, P.ssl, P.xB, P.hB, P.ruB,
                                             P.zB, P.cbB + blockIdx.x - P.cA,
                                             blockIdx.y, xls);
}

struct DuoGP {
    const unsigned* zA; const short8 *WhA, *WlA; const float* bA; float* ruA;
    const unsigned* zB; const short8 *WhB, *WlB; const float* bB; float* ruB;
};

__global__ __launch_bounds__(256)
void gate_duo(DuoGP P)
{
    if (blockIdx.z == 0)
        gate_body(P.zA, 224, P.WhA, P.WlA, P.bA, P.ruA, blockIdx.x, blockIdx.y * 4);
    else
        gate_body(P.zB, 384, P.WhB, P.WlB, P.bB, P.ruB, blockIdx.x, blockIdx.y * 4);
}

struct DuoCP {
    const unsigned* zA; const short8 *WhA, *WlA; const float* bA;
    const float* ruA; float* hA;
    const unsigned* zB; const short8 *WhB, *WlB; const float* bB;
    const float* ruB; float* hB;
};

__global__ __launch_bounds__(256)
void cand_duo(DuoCP P)
{
    if (blockIdx.z == 0)
        cand_body(P.zA, 224, P.WhA, P.WlA, P.bA, P.ruA, P.hA, blockIdx.x, blockIdx.y * 2);
    else
        cand_body(P.zB, 384, P.WhB, P.WlB, P.bB, P.ruB, P.hB, blockIdx.x, blockIdx.y * 2);
}

// ---------------- host launcher ----------------

extern "C" void kernel_launch(void* const* d_in, const int* in_sizes, int n_in,
                              void* d_out, int out_size, void* d_ws, size_t ws_size,
                              hipStream_t stream)
{
    const float* inputs = (const float*)d_in[0];
    const float* S      = (const float*)d_in[1];
    const float* Wt[4][4];
    for (int l = 0; l < 4; ++l)
        for (int j = 0; j < 4; ++j)
            Wt[l][j] = (const float*)d_in[2 + l * 4 + j];
    const float* pW = (const float*)d_in[18];
    const float* pb = (const float*)d_in[19];
    float* out = (float*)d_out;

    // workspace layout
    float*    ws     = (float*)d_ws;
    float*    h0     = ws;                         // BN*64
    float*    h1     = h0 + (size_t)BN * U;        // BN*64
    float*    dec_in = h1 + (size_t)BN * U;        // BN
    float*    ruA    = dec_in + BN;                // BN*128
    float*    ruB    = ruA + (size_t)BN * 128;     // BN*128
    unsigned* zcatA  = (unsigned*)(ruB + (size_t)BN * 128);  // BN*224
    unsigned* zcatB  = zcatA + (size_t)BN * 224;             // BN*384
    float*    S2     = (float*)(zcatB + (size_t)BN * 384);   // N*N
    char*     pp     = (char*)(S2 + (size_t)N * N);
    pp = (char*)(((uintptr_t)pp + 15) & ~(uintptr_t)15);

    short* ssh = (short*)pp;                       // 42*11*64*8 shorts
    short* ssl = ssh + (size_t)SSTIL * SSKC * 64 * 8;
    char*  wpbase = (char*)(ssl + (size_t)SSTIL * SSKC * 64 * 8);

    const int Fs[4]   = {66, 128, 65, 128};
    const int K3ps[4] = {224, 384, 224, 384};
    short *Wgh[4], *Wgl[4], *Wch[4], *Wcl[4];
    size_t off = 0;
    for (int l = 0; l < 4; ++l) {
        const size_t ge = (size_t)K3ps[l] * 128, ce = (size_t)K3ps[l] * 64;
        Wgh[l] = (short*)(wpbase + off); off += ge * 2;
        Wgl[l] = (short*)(wpbase + off); off += ge * 2;
        Wch[l] = (short*)(wpbase + off); off += ce * 2;
        Wcl[l] = (short*)(wpbase + off); off += ce * 2;
    }

    // zero state + both zcat buffers (pad strips must start finite; per replay)
    const long zn = (long)BN * (2 * U) + BN + (long)BN * 256 + (long)BN * (224 + 384);
    zero_kernel<<<2048, 256, 0, stream>>>((unsigned*)h0, zn);

    s2_build<<<N, 256, 0, stream>>>(S, S2);
    prepack_ss<<<dim3(SSTIL, SSKC), 64, 0, stream>>>(S, S2, ssh, ssl);
    for (int l = 0; l < 4; ++l) {
        prepack_w<<<dim3(K3ps[l] / 32, 8), 64, 0, stream>>>(Wt[l][0], Wgh[l], Wgl[l],
                                                            Fs[l], 128, 8);
        prepack_w<<<dim3(K3ps[l] / 32, 4), 64, 0, stream>>>(Wt[l][2], Wch[l], Wcl[l],
                                                            Fs[l], 64, 4);
    }

    const short8* SSH = (const short8*)ssh;
    const short8* SSL = (const short8*)ssl;

    // -------- encoder: software-pipelined (cell0 step s || cell1 step s-1) ----
    for (int s = 0; s <= T; ++s) {
        const float* x0 = inputs + (size_t)s * BN * 2;
        const bool a = (s < T), b1 = (s >= 1);
        if (a && b1) {
            DuoDP dp{SSH, SSL, x0, h0, nullptr, zcatA, h0, h1, nullptr, zcatB, 3, 0};
            diffuse_duo<false><<<dim3(7, B), 896, 0, stream>>>(dp);
            DuoGP gp{zcatA, (short8*)Wgh[0], (short8*)Wgl[0], Wt[0][1], ruA,
                     zcatB, (short8*)Wgh[1], (short8*)Wgl[1], Wt[1][1], ruB};
            gate_duo<<<dim3(BN / 64, 2, 2), 256, 0, stream>>>(gp);
            DuoDP dp2{SSH, SSL, x0, h0, ruA, zcatA, h0, h1, ruB, zcatB, 3, 2};
            diffuse_duo<true><<<dim3(5, B), 896, 0, stream>>>(dp2);
            DuoCP cp{zcatA, (short8*)Wch[0], (short8*)Wcl[0], Wt[0][3], ruA, h0,
                     zcatB, (short8*)Wch[1], (short8*)Wcl[1], Wt[1][3], ruB, h1};
            cand_duo<<<dim3(BN / 64, 2, 2), 256, 0, stream>>>(cp);
        } else if (a) {  // s == 0: cell0 solo
            diffuse_solo<2, 66, 224, false, 0, false><<<dim3(3, B), 896, 0, stream>>>(
                SSH, SSL, x0, h0, nullptr, zcatA);
            gate_solo<<<dim3(BN / 64, 2), 256, 0, stream>>>(
                zcatA, 224, (short8*)Wgh[0], (short8*)Wgl[0], Wt[0][1], ruA);
            diffuse_solo<2, 66, 224, true, 0, false><<<dim3(3, B), 896, 0, stream>>>(
                SSH, SSL, x0, h0, ruA, zcatA);
            cand_solo<<<dim3(BN / 64, 2), 256, 0, stream>>>(
                zcatA, 224, (short8*)Wch[0], (short8*)Wcl[0], Wt[0][3], ruA, h0);
        } else {         // s == T: cell1 drain
            diffuse_solo<64, 128, 384, false, 0, true><<<dim3(4, B), 896, 0, stream>>>(
                SSH, SSL, h0, h1, nullptr, zcatB);
            gate_solo<<<dim3(BN / 64, 2), 256, 0, stream>>>(
                zcatB, 384, (short8*)Wgh[1], (short8*)Wgl[1], Wt[1][1], ruB);
            diffuse_solo<64, 128, 384, true, 2, true><<<dim3(2, B), 896, 0, stream>>>(
                SSH, SSL, h0, h1, ruB, zcatB);
            cand_solo<<<dim3(BN / 64, 2), 256, 0, stream>>>(
                zcatB, 384, (short8*)Wch[1], (short8*)Wcl[1], Wt[1][3], ruB, h1);
        }
    }

    // -------- decoder (sequential; D2 layer-1 computes h-cols only) --------
    for (int hz = 0; hz < HZ; ++hz) {
        diffuse_solo<1, 65, 224, false, 0, false><<<dim3(3, B), 896, 0, stream>>>(
            SSH, SSL, dec_in, h0, nullptr, zcatB);
        gate_solo<<<dim3(BN / 64, 2), 256, 0, stream>>>(
            zcatB, 224, (short8*)Wgh[2], (short8*)Wgl[2], Wt[2][1], ruA);
        diffuse_solo<1, 65, 224, true, 0, false><<<dim3(3, B), 896, 0, stream>>>(
            SSH, SSL, dec_in, h0, ruA, zcatB);
        cand_solo<<<dim3(BN / 64, 2), 256, 0, stream>>>(
            zcatB, 224, (short8*)Wch[2], (short8*)Wcl[2], Wt[2][3], ruA, h0);
        diffuse_solo<64, 128, 384, false, 0, true><<<dim3(4, B), 896, 0, stream>>>(
            SSH, SSL, h0, h1, nullptr, zcatB);
        gate_solo<<<dim3(BN / 64, 2), 256, 0, stream>>>(
            zcatB, 384, (short8*)Wgh[3], (short8*)Wgl[3], Wt[3][1], ruA);
        diffuse_solo<64, 128, 384, true, 2, true><<<dim3(2, B), 896, 0, stream>>>(
            SSH, SSL, h0, h1, ruA, zcatB);
        cand_proj<<<BN / 64, 256, 0, stream>>>(
            zcatB, 384, (short8*)Wch[3], (short8*)Wcl[3], Wt[3][3], ruA, h1,
            pW, pb, out + (size_t)hz * BN, dec_in);
    }
}

// Round 10
// 3971.864 us; speedup vs baseline: 2.7703x; 1.0273x over previous
//
#include <hip/hip_runtime.h>

// ---------------- problem constants ----------------
constexpr int N  = 325;   // nodes
constexpr int B  = 64;    // batch
constexpr int T  = 12;    // encoder steps
constexpr int HZ = 12;    // decoder horizon
constexpr int U  = 64;    // rnn units
constexpr int BN = B * N; // 20800 rows

// SS = [S ; S^2] stacked: rows [0,325)=S, [336,661)=S^2 (42 tiles of 16)
constexpr int SSTIL = 42;
constexpr int SSKC  = 11;   // K chunks of 32 (K padded 325->352)
constexpr int XST   = 364;  // u32 stride per feature column in diffuse LDS

typedef __attribute__((ext_vector_type(8))) short short8;
typedef __attribute__((ext_vector_type(4))) float floatx4;

// bf16 round-to-nearest-even + hi/lo split helpers
__device__ inline unsigned short f2bf(float f) {
    unsigned u = __float_as_uint(f);
    u += 0x7fff + ((u >> 16) & 1);
    return (unsigned short)(u >> 16);
}
__device__ inline unsigned pack_hilo(float v) {
    const unsigned short hi = f2bf(v);
    const float hif = __uint_as_float(((unsigned)hi) << 16);
    const unsigned short lo = f2bf(v - hif);
    return (unsigned)hi | ((unsigned)lo << 16);
}
__device__ inline void unpack8(const uint4 u0, const uint4 u1,
                               short8& h, short8& l) {
    const unsigned uu[8] = {u0.x, u0.y, u0.z, u0.w, u1.x, u1.y, u1.z, u1.w};
    #pragma unroll
    for (int j = 0; j < 8; ++j) {
        h[j] = (short)(uu[j] & 0xffffu);
        l[j] = (short)(uu[j] >> 16);
    }
}

// ---------------- setup kernels ----------------

__global__ void zero_kernel(unsigned* __restrict__ p, long n) {
    long i = (long)blockIdx.x * blockDim.x + threadIdx.x;
    const long stride = (long)gridDim.x * blockDim.x;
    for (; i < n; i += stride) p[i] = 0u;
}

// S2 = S @ S (fp32). One block per output row.
__global__ __launch_bounds__(256)
void s2_build(const float* __restrict__ S, float* __restrict__ S2)
{
    const int m = blockIdx.x;
    __shared__ float srow[N];
    for (int i = threadIdx.x; i < N; i += 256) srow[i] = S[m * N + i];
    __syncthreads();
    for (int c = threadIdx.x; c < N; c += 256) {
        float a = 0.f;
        for (int k = 0; k < N; ++k) a += srow[k] * S[k * N + c];
        S2[m * N + c] = a;
    }
}

// Prepack SS=[S;S2] into MFMA A-fragments (bf16 hi/lo).
__global__ __launch_bounds__(64)
void prepack_ss(const float* __restrict__ S, const float* __restrict__ S2,
                short* __restrict__ ssh, short* __restrict__ ssl)
{
    const int t = blockIdx.x, kc = blockIdx.y, lane = threadIdx.x;
    const int quad = lane >> 4, l15 = lane & 15;
    short8 hv, lv;
    #pragma unroll
    for (int j = 0; j < 8; ++j) {
        const int m = t * 16 + l15;
        const int k = kc * 32 + quad * 8 + j;
        float v = 0.f;
        if (k < N) {
            if (m < N) v = S[m * N + k];
            else if (m >= 336 && m < 336 + N) v = S2[(m - 336) * N + k];
        }
        const unsigned short hb = f2bf(v);
        hv[j] = (short)hb;
        lv[j] = (short)f2bf(v - __uint_as_float(((unsigned)hb) << 16));
    }
    const size_t off = ((size_t)(t * SSKC + kc) * 64 + lane);
    ((short8*)ssh)[off] = hv;
    ((short8*)ssl)[off] = lv;
}

// Prepack weights into MFMA B-fragment order, bf16 hi/lo, for K-layout
// [ z0-slices (Z0KC*32, from x/h, fold W0'=W0-W2) | y1 (F, W1) | y2 (F, 2*W2) ]
// zero rows elsewhere.
__global__ __launch_bounds__(64)
void prepack_w(const float* __restrict__ W, short* __restrict__ Wh,
               short* __restrict__ Wl, int F, int Nout, int NT, int Z0KC)
{
    const int kc = blockIdx.x, n = blockIdx.y, lane = threadIdx.x;
    const int quad = lane >> 4, l15 = lane & 15;
    short8 hv, lv;
    #pragma unroll
    for (int j = 0; j < 8; ++j) {
        const int p   = kc * 32 + quad * 8 + j;
        const int col = n * 16 + l15;
        float w = 0.f;
        if (p < Z0KC * 32) {
            const int f = p;
            if (f < F)
                w = W[(size_t)f * Nout + col] - W[(size_t)(2 * F + f) * Nout + col];
        } else {
            const int q = p - Z0KC * 32;
            if (q < F)
                w = W[(size_t)(F + q) * Nout + col];
            else if (q < 2 * F)
                w = 2.f * W[(size_t)(2 * F + (q - F)) * Nout + col];
        }
        const unsigned short hb = f2bf(w);
        hv[j] = (short)hb;
        lv[j] = (short)f2bf(w - __uint_as_float(((unsigned)hb) << 16));
    }
    const size_t off = ((size_t)(kc * NT + n) * 64 + lane);
    ((short8*)Wh)[off] = hv;
    ((short8*)Wl)[off] = lv;
}

// ---------------- z0 A-fragment builder (bit-identical to old pack path) ----
template<int DIN, int F, bool RM, bool ZV>
__device__ __forceinline__ void z0_frag(const float* __restrict__ x,
    const float* __restrict__ h, const float* __restrict__ ru,
    int row, int kc, int quad, short8& ah, short8& al)
{
    float v[8];
    if constexpr (ZV) {   // DIN==64, F==128: aligned float4 path
        const int k0 = kc * 32 + quad * 8;
        if (k0 < 64) {
            const float4 a = *(const float4*)&x[(size_t)row * 64 + k0];
            const float4 b = *(const float4*)&x[(size_t)row * 64 + k0 + 4];
            v[0]=a.x; v[1]=a.y; v[2]=a.z; v[3]=a.w;
            v[4]=b.x; v[5]=b.y; v[6]=b.z; v[7]=b.w;
        } else {
            const int kk = k0 - 64;
            float4 a = *(const float4*)&h[(size_t)row * 64 + kk];
            float4 b = *(const float4*)&h[(size_t)row * 64 + kk + 4];
            if constexpr (RM) {
                const float4 ra = *(const float4*)&ru[(size_t)row * 128 + kk];
                const float4 rb = *(const float4*)&ru[(size_t)row * 128 + kk + 4];
                a.x *= ra.x; a.y *= ra.y; a.z *= ra.z; a.w *= ra.w;
                b.x *= rb.x; b.y *= rb.y; b.z *= rb.z; b.w *= rb.w;
            }
            v[0]=a.x; v[1]=a.y; v[2]=a.z; v[3]=a.w;
            v[4]=b.x; v[5]=b.y; v[6]=b.z; v[7]=b.w;
        }
    } else {
        #pragma unroll
        for (int j = 0; j < 8; ++j) {
            const int k = kc * 32 + quad * 8 + j;
            float t = 0.f;
            if (k < DIN) t = x[(size_t)row * DIN + k];
            else if (k < F) {
                t = h[(size_t)row * 64 + (k - DIN)];
                if constexpr (RM) t *= ru[(size_t)row * 128 + (k - DIN)];
            }
            v[j] = t;
        }
    }
    #pragma unroll
    for (int j = 0; j < 8; ++j) {
        const unsigned u = pack_hilo(v[j]);
        ah[j] = (short)(u & 0xffffu);
        al[j] = (short)(u >> 16);
    }
}

// ---------------- diffusion GEMM body (y-only zcat) ----------------
// Y = SS @ X_b for one (batch, 32-col chunk cx). 896 thr, 14 waves x 3 tiles.
// Writes ONLY y1|y2 (pitch YP): y1 at col, y2 at F+col. No z0 section.
template<int DIN, int F, int YP, bool RMUL, bool VEC>
__device__ __forceinline__ void diffuse_body(
    const short8* __restrict__ ssh, const short8* __restrict__ ssl,
    const float* __restrict__ x, const float* __restrict__ h,
    const float* __restrict__ ru, unsigned* __restrict__ zcat,
    int cx, int b, unsigned* __restrict__ xls)
{
    const int c0 = cx * 32;
    const int tid = threadIdx.x, wave = tid >> 6, lane = tid & 63;
    const int quad = lane >> 4, l15 = lane & 15;

    if constexpr (VEC) {
        for (int idx4 = tid; idx4 < 352 * 8; idx4 += 896) {
            const int n = idx4 >> 3, f = (idx4 & 7) * 4, gf = c0 + f;
            uint4 pk = make_uint4(0u, 0u, 0u, 0u);
            if (n < N) {
                const int row = b * N + n;
                float4 v;
                if (gf < DIN) {
                    v = *(const float4*)&x[(size_t)row * DIN + gf];
                } else {
                    v = *(const float4*)&h[(size_t)row * U + (gf - DIN)];
                    if (RMUL) {
                        const float4 rv = *(const float4*)&ru[(size_t)row * 128 + (gf - DIN)];
                        v.x *= rv.x; v.y *= rv.y; v.z *= rv.z; v.w *= rv.w;
                    }
                }
                pk.x = pack_hilo(v.x); pk.y = pack_hilo(v.y);
                pk.z = pack_hilo(v.z); pk.w = pack_hilo(v.w);
            }
            xls[(f + 0) * XST + n] = pk.x;
            xls[(f + 1) * XST + n] = pk.y;
            xls[(f + 2) * XST + n] = pk.z;
            xls[(f + 3) * XST + n] = pk.w;
        }
    } else {
        for (int idx = tid; idx < 352 * 32; idx += 896) {
            const int n = idx >> 5, f = idx & 31, gf = c0 + f;
            unsigned u = 0u;
            if (n < N && gf < F) {
                const int row = b * N + n;
                float v;
                if (gf < DIN) {
                    v = x[(size_t)row * DIN + gf];
                } else {
                    v = h[(size_t)row * U + (gf - DIN)];
                    if (RMUL) v *= ru[(size_t)row * 128 + (gf - DIN)];
                }
                u = pack_hilo(v);
            }
            xls[f * XST + n] = u;
        }
    }
    __syncthreads();

    const int tb = wave * 3;  // 3 row tiles per wave, 14 waves -> 42 tiles

    floatx4 acc[3][2];
    #pragma unroll
    for (int i = 0; i < 3; ++i)
        #pragma unroll
        for (int n = 0; n < 2; ++n)
            acc[i][n] = (floatx4){0.f, 0.f, 0.f, 0.f};

    short8 cah[3], cal[3], nah[3], nal[3];
    #pragma unroll
    for (int i = 0; i < 3; ++i) {
        const size_t fo = (size_t)((tb + i) * SSKC) * 64 + lane;
        cah[i] = ssh[fo]; cal[i] = ssl[fo];
    }
    for (int kc = 0; kc < SSKC; ++kc) {
        if (kc + 1 < SSKC) {
            #pragma unroll
            for (int i = 0; i < 3; ++i) {
                const size_t fo = (size_t)((tb + i) * SSKC + kc + 1) * 64 + lane;
                nah[i] = ssh[fo]; nal[i] = ssl[fo];
            }
        }
        short8 bh[2], bl[2];
        const int koff = kc * 32 + quad * 8;
        #pragma unroll
        for (int n = 0; n < 2; ++n) {
            const uint4 u0 = *(const uint4*)&xls[(n * 16 + l15) * XST + koff];
            const uint4 u1 = *(const uint4*)&xls[(n * 16 + l15) * XST + koff + 4];
            unpack8(u0, u1, bh[n], bl[n]);
        }
        #pragma unroll
        for (int i = 0; i < 3; ++i)
            #pragma unroll
            for (int n = 0; n < 2; ++n) {
                acc[i][n] = __builtin_amdgcn_mfma_f32_16x16x32_bf16(cah[i], bh[n], acc[i][n], 0, 0, 0);
                acc[i][n] = __builtin_amdgcn_mfma_f32_16x16x32_bf16(cah[i], bl[n], acc[i][n], 0, 0, 0);
                acc[i][n] = __builtin_amdgcn_mfma_f32_16x16x32_bf16(cal[i], bh[n], acc[i][n], 0, 0, 0);
            }
        if (kc + 1 < SSKC) {
            #pragma unroll
            for (int i = 0; i < 3; ++i) { cah[i] = nah[i]; cal[i] = nal[i]; }
        }
    }

    #pragma unroll
    for (int i = 0; i < 3; ++i) {
        const int t = tb + i;
        #pragma unroll
        for (int n = 0; n < 2; ++n) {
            const int col = c0 + n * 16 + l15;
            if (col >= F) continue;
            #pragma unroll
            for (int r = 0; r < 4; ++r) {
                const int m = t * 16 + quad * 4 + r;
                if (m < N)
                    zcat[(size_t)(b * N + m) * YP + col] = pack_hilo(acc[i][n][r]);
                else if (m >= 336 && m < 336 + N)
                    zcat[(size_t)(b * N + (m - 336)) * YP + F + col] = pack_hilo(acc[i][n][r]);
            }
        }
    }
}

// ---------------- dense GEMM bodies (z0 from globals, y from zcat) ----------

// Gate: ru = sigmoid([z0|y1|y2] @ Wg + b). nb = col-tile base (0 or 4).
template<int DIN, int F, int Z0KC, int YKC, bool ZV>
__device__ __forceinline__ void gate_body(const unsigned* __restrict__ zcat,
    const float* __restrict__ x, const float* __restrict__ h,
    const short8* __restrict__ Wh, const short8* __restrict__ Wl,
    const float* __restrict__ bias, float* __restrict__ ruout, int bx, int nb)
{
    constexpr int YP = YKC * 32, NT = 4;
    const int tid = threadIdx.x, wave = tid >> 6, lane = tid & 63;
    const int quad = lane >> 4, l15 = lane & 15;
    const int row0 = bx * 64 + wave * 16;
    const int row = row0 + l15;

    floatx4 acc[NT];
    #pragma unroll
    for (int n = 0; n < NT; ++n) {
        const float bv = bias[(nb + n) * 16 + l15];
        acc[n] = (floatx4){bv, bv, bv, bv};
    }
    for (int kc = 0; kc < Z0KC; ++kc) {
        short8 ahi, alo;
        z0_frag<DIN, F, false, ZV>(x, h, nullptr, row, kc, quad, ahi, alo);
        const short8* __restrict__ wh = Wh + (size_t)(kc * 8 + nb) * 64 + lane;
        const short8* __restrict__ wl = Wl + (size_t)(kc * 8 + nb) * 64 + lane;
        #pragma unroll
        for (int n = 0; n < NT; ++n) {
            const short8 bh = wh[n * 64], bl = wl[n * 64];
            acc[n] = __builtin_amdgcn_mfma_f32_16x16x32_bf16(ahi, bh, acc[n], 0, 0, 0);
            acc[n] = __builtin_amdgcn_mfma_f32_16x16x32_bf16(ahi, bl, acc[n], 0, 0, 0);
            acc[n] = __builtin_amdgcn_mfma_f32_16x16x32_bf16(alo, bh, acc[n], 0, 0, 0);
        }
    }
    const unsigned* __restrict__ zrow = zcat + (size_t)row * YP + quad * 8;
    for (int kc = 0; kc < YKC; ++kc) {
        const uint4* p = (const uint4*)(zrow + kc * 32);
        short8 ahi, alo;
        unpack8(p[0], p[1], ahi, alo);
        const short8* __restrict__ wh = Wh + (size_t)((Z0KC + kc) * 8 + nb) * 64 + lane;
        const short8* __restrict__ wl = Wl + (size_t)((Z0KC + kc) * 8 + nb) * 64 + lane;
        #pragma unroll
        for (int n = 0; n < NT; ++n) {
            const short8 bh = wh[n * 64], bl = wl[n * 64];
            acc[n] = __builtin_amdgcn_mfma_f32_16x16x32_bf16(ahi, bh, acc[n], 0, 0, 0);
            acc[n] = __builtin_amdgcn_mfma_f32_16x16x32_bf16(ahi, bl, acc[n], 0, 0, 0);
            acc[n] = __builtin_amdgcn_mfma_f32_16x16x32_bf16(alo, bh, acc[n], 0, 0, 0);
        }
    }
    #pragma unroll
    for (int n = 0; n < NT; ++n) {
        const int col = (nb + n) * 16 + l15;
        #pragma unroll
        for (int r = 0; r < 4; ++r) {
            const int rw = row0 + quad * 4 + r;
            ruout[(size_t)rw * 128 + col] = 1.f / (1.f + __expf(-acc[n][r]));
        }
    }
}

// Candidate: c = tanh([z0r|y1|y2] @ Wc + b); hout = u*h + (1-u)*c. nb = 0/2.
template<int DIN, int F, int Z0KC, int YKC, bool ZV>
__device__ __forceinline__ void cand_body(const unsigned* __restrict__ zcat,
    const float* __restrict__ x, const float* __restrict__ h,
    const float* __restrict__ ru, const short8* __restrict__ Wh,
    const short8* __restrict__ Wl, const float* __restrict__ bias,
    float* __restrict__ hout, int bx, int nb)
{
    constexpr int YP = YKC * 32, NT = 2;
    const int tid = threadIdx.x, wave = tid >> 6, lane = tid & 63;
    const int quad = lane >> 4, l15 = lane & 15;
    const int row0 = bx * 64 + wave * 16;
    const int row = row0 + l15;

    floatx4 acc[NT];
    #pragma unroll
    for (int n = 0; n < NT; ++n) {
        const float bv = bias[(nb + n) * 16 + l15];
        acc[n] = (floatx4){bv, bv, bv, bv};
    }
    for (int kc = 0; kc < Z0KC; ++kc) {
        short8 ahi, alo;
        z0_frag<DIN, F, true, ZV>(x, h, ru, row, kc, quad, ahi, alo);
        const short8* __restrict__ wh = Wh + (size_t)(kc * 4 + nb) * 64 + lane;
        const short8* __restrict__ wl = Wl + (size_t)(kc * 4 + nb) * 64 + lane;
        #pragma unroll
        for (int n = 0; n < NT; ++n) {
            const short8 bh = wh[n * 64], bl = wl[n * 64];
            acc[n] = __builtin_amdgcn_mfma_f32_16x16x32_bf16(ahi, bh, acc[n], 0, 0, 0);
            acc[n] = __builtin_amdgcn_mfma_f32_16x16x32_bf16(ahi, bl, acc[n], 0, 0, 0);
            acc[n] = __builtin_amdgcn_mfma_f32_16x16x32_bf16(alo, bh, acc[n], 0, 0, 0);
        }
    }
    const unsigned* __restrict__ zrow = zcat + (size_t)row * YP + quad * 8;
    for (int kc = 0; kc < YKC; ++kc) {
        const uint4* p = (const uint4*)(zrow + kc * 32);
        short8 ahi, alo;
        unpack8(p[0], p[1], ahi, alo);
        const short8* __restrict__ wh = Wh + (size_t)((Z0KC + kc) * 4 + nb) * 64 + lane;
        const short8* __restrict__ wl = Wl + (size_t)((Z0KC + kc) * 4 + nb) * 64 + lane;
        #pragma unroll
        for (int n = 0; n < NT; ++n) {
            const short8 bh = wh[n * 64], bl = wl[n * 64];
            acc[n] = __builtin_amdgcn_mfma_f32_16x16x32_bf16(ahi, bh, acc[n], 0, 0, 0);
            acc[n] = __builtin_amdgcn_mfma_f32_16x16x32_bf16(ahi, bl, acc[n], 0, 0, 0);
            acc[n] = __builtin_amdgcn_mfma_f32_16x16x32_bf16(alo, bh, acc[n], 0, 0, 0);
        }
    }
    #pragma unroll
    for (int n = 0; n < NT; ++n) {
        const int col = (nb + n) * 16 + l15;
        #pragma unroll
        for (int r = 0; r < 4; ++r) {
            const int rw = row0 + quad * 4 + r;
            const float c  = tanhf(acc[n][r]);
            const float ug = ru[(size_t)rw * 128 + 64 + col];  // u = ru[:,64:]
            const float hv = h[(size_t)rw * 64 + col];
            hout[(size_t)rw * 64 + col] = ug * hv + (1.f - ug) * c;
        }
    }
}

// ---------------- solo kernels ----------------

template<int DIN, int F, int YP, bool RMUL, int CB, bool VEC>
__global__ __launch_bounds__(896, 7)
void diffuse_solo(const short8* __restrict__ ssh, const short8* __restrict__ ssl,
                  const float* __restrict__ x, const float* __restrict__ h,
                  const float* __restrict__ ru, unsigned* __restrict__ zcat)
{
    __shared__ __align__(16) unsigned xls[32 * XST];
    diffuse_body<DIN, F, YP, RMUL, VEC>(ssh, ssl, x, h, ru, zcat,
                                        CB + blockIdx.x, blockIdx.y, xls);
}

template<int DIN, int F, int Z0KC, int YKC, bool ZV>
__global__ __launch_bounds__(256)
void gate_cell(const unsigned* __restrict__ zcat, const float* __restrict__ x,
               const float* __restrict__ h, const short8* __restrict__ Wh,
               const short8* __restrict__ Wl, const float* __restrict__ bias,
               float* __restrict__ ru)
{
    gate_body<DIN, F, Z0KC, YKC, ZV>(zcat, x, h, Wh, Wl, bias, ru,
                                     blockIdx.x, blockIdx.y * 4);
}

template<int DIN, int F, int Z0KC, int YKC, bool ZV>
__global__ __launch_bounds__(256)
void cand_cell(const unsigned* __restrict__ zcat, const float* __restrict__ x,
               const float* __restrict__ h, const float* __restrict__ ru,
               const short8* __restrict__ Wh, const short8* __restrict__ Wl,
               const float* __restrict__ bias, float* __restrict__ hout)
{
    cand_body<DIN, F, Z0KC, YKC, ZV>(zcat, x, h, ru, Wh, Wl, bias, hout,
                                     blockIdx.x, blockIdx.y * 2);
}

// Candidate + fused projection (decoder layer 1, L1 geometry). NT=4 unsplit.
__global__ __launch_bounds__(256)
void cand_proj(const unsigned* __restrict__ zcat, const float* __restrict__ x,
               const float* __restrict__ h, const float* __restrict__ ru,
               const short8* __restrict__ Wh, const short8* __restrict__ Wl,
               const float* __restrict__ bias, float* __restrict__ hout,
               const float* __restrict__ pW, const float* __restrict__ pb,
               float* __restrict__ outp, float* __restrict__ dec_in)
{
    constexpr int Z0KC = 4, YKC = 8, YP = 256, NT = 4;
    const int tid = threadIdx.x, wave = tid >> 6, lane = tid & 63;
    const int quad = lane >> 4, l15 = lane & 15;
    const int row0 = blockIdx.x * 64 + wave * 16;
    const int row = row0 + l15;

    floatx4 acc[NT];
    #pragma unroll
    for (int n = 0; n < NT; ++n) {
        const float bv = bias[n * 16 + l15];
        acc[n] = (floatx4){bv, bv, bv, bv};
    }
    for (int kc = 0; kc < Z0KC; ++kc) {
        short8 ahi, alo;
        z0_frag<64, 128, true, true>(x, h, ru, row, kc, quad, ahi, alo);
        const short8* __restrict__ wh = Wh + (size_t)(kc * 4) * 64 + lane;
        const short8* __restrict__ wl = Wl + (size_t)(kc * 4) * 64 + lane;
        #pragma unroll
        for (int n = 0; n < NT; ++n) {
            const short8 bh = wh[n * 64], bl = wl[n * 64];
            acc[n] = __builtin_amdgcn_mfma_f32_16x16x32_bf16(ahi, bh, acc[n], 0, 0, 0);
            acc[n] = __builtin_amdgcn_mfma_f32_16x16x32_bf16(ahi, bl, acc[n], 0, 0, 0);
            acc[n] = __builtin_amdgcn_mfma_f32_16x16x32_bf16(alo, bh, acc[n], 0, 0, 0);
        }
    }
    const unsigned* __restrict__ zrow = zcat + (size_t)row * YP + quad * 8;
    for (int kc = 0; kc < YKC; ++kc) {
        const uint4* p = (const uint4*)(zrow + kc * 32);
        short8 ahi, alo;
        unpack8(p[0], p[1], ahi, alo);
        const short8* __restrict__ wh = Wh + (size_t)((Z0KC + kc) * 4) * 64 + lane;
        const short8* __restrict__ wl = Wl + (size_t)((Z0KC + kc) * 4) * 64 + lane;
        #pragma unroll
        for (int n = 0; n < NT; ++n) {
            const short8 bh = wh[n * 64], bl = wl[n * 64];
            acc[n] = __builtin_amdgcn_mfma_f32_16x16x32_bf16(ahi, bh, acc[n], 0, 0, 0);
            acc[n] = __builtin_amdgcn_mfma_f32_16x16x32_bf16(ahi, bl, acc[n], 0, 0, 0);
            acc[n] = __builtin_amdgcn_mfma_f32_16x16x32_bf16(alo, bh, acc[n], 0, 0, 0);
        }
    }
    float pr[4] = {0.f, 0.f, 0.f, 0.f};
    #pragma unroll
    for (int n = 0; n < NT; ++n) {
        const int col = n * 16 + l15;
        const float pw = pW[col];
        #pragma unroll
        for (int r = 0; r < 4; ++r) {
            const int rw = row0 + quad * 4 + r;
            const float c  = tanhf(acc[n][r]);
            const float ug = ru[(size_t)rw * 128 + 64 + col];
            const float hv = h[(size_t)rw * 64 + col];
            const float hn = ug * hv + (1.f - ug) * c;
            hout[(size_t)rw * 64 + col] = hn;
            pr[r] += hn * pw;
        }
    }
    #pragma unroll
    for (int r = 0; r < 4; ++r) {
        float v = pr[r];
        v += __shfl_xor(v, 1); v += __shfl_xor(v, 2);
        v += __shfl_xor(v, 4); v += __shfl_xor(v, 8);
        if (l15 == 0) {
            const int rw = row0 + quad * 4 + r;
            const float o = v + pb[0];
            outp[rw]   = o;
            dec_in[rw] = o;
        }
    }
}

// ---------------- duo kernels (encoder pipelining) ----------------

struct DuoDP {
    const short8 *ssh, *ssl;
    const float *xA, *hA, *ruA; unsigned* zA;
    const float *xB, *hB, *ruB; unsigned* zB;
    int cA, cbB;
};

template<bool RM>
__global__ __launch_bounds__(896, 7)
void diffuse_duo(DuoDP P)
{
    __shared__ __align__(16) unsigned xls[32 * XST];
    if ((int)blockIdx.x < P.cA)
        diffuse_body<2, 66, 160, RM, false>(P.ssh, P.ssl, P.xA, P.hA, P.ruA,
                                            P.zA, blockIdx.x, blockIdx.y, xls);
    else
        diffuse_body<64, 128, 256, RM, true>(P.ssh, P.ssl, P.xB, P.hB, P.ruB,
                                             P.zB, P.cbB + blockIdx.x - P.cA,
                                             blockIdx.y, xls);
}

struct DuoGP {
    const unsigned* zA; const float *xA, *hA;
    const short8 *WhA, *WlA; const float* bA; float* ruA;
    const unsigned* zB; const float *xB, *hB;
    const short8 *WhB, *WlB; const float* bB; float* ruB;
};

__global__ __launch_bounds__(256)
void gate_duo(DuoGP P)
{
    if (blockIdx.z == 0)
        gate_body<2, 66, 3, 5, false>(P.zA, P.xA, P.hA, P.WhA, P.WlA, P.bA,
                                      P.ruA, blockIdx.x, blockIdx.y * 4);
    else
        gate_body<64, 128, 4, 8, true>(P.zB, P.xB, P.hB, P.WhB, P.WlB, P.bB,
                                       P.ruB, blockIdx.x, blockIdx.y * 4);
}

struct DuoCP {
    const unsigned* zA; const float *xA, *hA, *ruA;
    const short8 *WhA, *WlA; const float* bA; float* hoA;
    const unsigned* zB; const float *xB, *hB, *ruB;
    const short8 *WhB, *WlB; const float* bB; float* hoB;
};

__global__ __launch_bounds__(256)
void cand_duo(DuoCP P)
{
    if (blockIdx.z == 0)
        cand_body<2, 66, 3, 5, false>(P.zA, P.xA, P.hA, P.ruA, P.WhA, P.WlA,
                                      P.bA, P.hoA, blockIdx.x, blockIdx.y * 2);
    else
        cand_body<64, 128, 4, 8, true>(P.zB, P.xB, P.hB, P.ruB, P.WhB, P.WlB,
                                       P.bB, P.hoB, blockIdx.x, blockIdx.y * 2);
}

// ---------------- host launcher ----------------

extern "C" void kernel_launch(void* const* d_in, const int* in_sizes, int n_in,
                              void* d_out, int out_size, void* d_ws, size_t ws_size,
                              hipStream_t stream)
{
    const float* inputs = (const float*)d_in[0];
    const float* S      = (const float*)d_in[1];
    const float* Wt[4][4];
    for (int l = 0; l < 4; ++l)
        for (int j = 0; j < 4; ++j)
            Wt[l][j] = (const float*)d_in[2 + l * 4 + j];
    const float* pW = (const float*)d_in[18];
    const float* pb = (const float*)d_in[19];
    float* out = (float*)d_out;

    // workspace layout (ping-pong h; y-only zcat)
    float*    ws     = (float*)d_ws;
    float*    H0[2]  = {ws, ws + (size_t)BN * U};
    float*    H1[2]  = {ws + 2 * (size_t)BN * U, ws + 3 * (size_t)BN * U};
    float*    dec_in = ws + 4 * (size_t)BN * U;            // BN
    float*    ruA    = dec_in + BN;                        // BN*128
    float*    ruB    = ruA + (size_t)BN * 128;             // BN*128
    unsigned* zcatA  = (unsigned*)(ruB + (size_t)BN * 128);  // BN*160
    unsigned* zcatB  = zcatA + (size_t)BN * 160;             // BN*256
    float*    S2     = (float*)(zcatB + (size_t)BN * 256);   // N*N
    char*     pp     = (char*)(S2 + (size_t)N * N);
    pp = (char*)(((uintptr_t)pp + 15) & ~(uintptr_t)15);

    short* ssh = (short*)pp;                       // 42*11*64*8 shorts
    short* ssl = ssh + (size_t)SSTIL * SSKC * 64 * 8;
    char*  wpbase = (char*)(ssl + (size_t)SSTIL * SSKC * 64 * 8);

    // K layouts: [z0 pad | y1 | y2 pad]; L0: 3+5 kc = 256, L1: 4+8 kc = 384
    const int Fs[4]   = {66, 128, 65, 128};
    const int KPs[4]  = {256, 384, 256, 384};
    const int Z0s[4]  = {3, 4, 3, 4};
    short *Wgh[4], *Wgl[4], *Wch[4], *Wcl[4];
    size_t off = 0;
    for (int l = 0; l < 4; ++l) {
        const size_t ge = (size_t)KPs[l] * 128, ce = (size_t)KPs[l] * 64;
        Wgh[l] = (short*)(wpbase + off); off += ge * 2;
        Wgl[l] = (short*)(wpbase + off); off += ge * 2;
        Wch[l] = (short*)(wpbase + off); off += ce * 2;
        Wcl[l] = (short*)(wpbase + off); off += ce * 2;
    }

    // zero state + zcat (first-use NaN-safety; pads stay finite thereafter)
    const long zn = (long)BN * (4 * U) + BN + (long)BN * 256 + (long)BN * (160 + 256);
    zero_kernel<<<2048, 256, 0, stream>>>((unsigned*)ws, zn);

    s2_build<<<N, 256, 0, stream>>>(S, S2);
    prepack_ss<<<dim3(SSTIL, SSKC), 64, 0, stream>>>(S, S2, ssh, ssl);
    for (int l = 0; l < 4; ++l) {
        prepack_w<<<dim3(KPs[l] / 32, 8), 64, 0, stream>>>(Wt[l][0], Wgh[l], Wgl[l],
                                                           Fs[l], 128, 8, Z0s[l]);
        prepack_w<<<dim3(KPs[l] / 32, 4), 64, 0, stream>>>(Wt[l][2], Wch[l], Wcl[l],
                                                           Fs[l], 64, 4, Z0s[l]);
    }

    const short8* SSH = (const short8*)ssh;
    const short8* SSL = (const short8*)ssl;
    int p0 = 0, p1 = 0;

    // -------- encoder: software-pipelined (cell0 step s || cell1 step s-1) ----
    for (int s = 0; s <= T; ++s) {
        const float* x0 = inputs + (size_t)s * BN * 2;
        const bool a = (s < T), b1 = (s >= 1);
        if (a && b1) {
            DuoDP dp{SSH, SSL, x0, H0[p0], nullptr, zcatA,
                     H0[p0], H1[p1], nullptr, zcatB, 3, 0};
            diffuse_duo<false><<<dim3(7, B), 896, 0, stream>>>(dp);
            DuoGP gp{zcatA, x0, H0[p0], (short8*)Wgh[0], (short8*)Wgl[0], Wt[0][1], ruA,
                     zcatB, H0[p0], H1[p1], (short8*)Wgh[1], (short8*)Wgl[1], Wt[1][1], ruB};
            gate_duo<<<dim3(BN / 64, 2, 2), 256, 0, stream>>>(gp);
            DuoDP dp2{SSH, SSL, x0, H0[p0], ruA, zcatA,
                      H0[p0], H1[p1], ruB, zcatB, 3, 2};
            diffuse_duo<true><<<dim3(5, B), 896, 0, stream>>>(dp2);
            DuoCP cp{zcatA, x0, H0[p0], ruA, (short8*)Wch[0], (short8*)Wcl[0], Wt[0][3], H0[p0 ^ 1],
                     zcatB, H0[p0], H1[p1], ruB, (short8*)Wch[1], (short8*)Wcl[1], Wt[1][3], H1[p1 ^ 1]};
            cand_duo<<<dim3(BN / 64, 2, 2), 256, 0, stream>>>(cp);
            p0 ^= 1; p1 ^= 1;
        } else if (a) {  // s == 0: cell0 solo
            diffuse_solo<2, 66, 160, false, 0, false><<<dim3(3, B), 896, 0, stream>>>(
                SSH, SSL, x0, H0[p0], nullptr, zcatA);
            gate_cell<2, 66, 3, 5, false><<<dim3(BN / 64, 2), 256, 0, stream>>>(
                zcatA, x0, H0[p0], (short8*)Wgh[0], (short8*)Wgl[0], Wt[0][1], ruA);
            diffuse_solo<2, 66, 160, true, 0, false><<<dim3(3, B), 896, 0, stream>>>(
                SSH, SSL, x0, H0[p0], ruA, zcatA);
            cand_cell<2, 66, 3, 5, false><<<dim3(BN / 64, 2), 256, 0, stream>>>(
                zcatA, x0, H0[p0], ruA, (short8*)Wch[0], (short8*)Wcl[0], Wt[0][3], H0[p0 ^ 1]);
            p0 ^= 1;
        } else {         // s == T: cell1 drain
            diffuse_solo<64, 128, 256, false, 0, true><<<dim3(4, B), 896, 0, stream>>>(
                SSH, SSL, H0[p0], H1[p1], nullptr, zcatB);
            gate_cell<64, 128, 4, 8, true><<<dim3(BN / 64, 2), 256, 0, stream>>>(
                zcatB, H0[p0], H1[p1], (short8*)Wgh[1], (short8*)Wgl[1], Wt[1][1], ruB);
            diffuse_solo<64, 128, 256, true, 2, true><<<dim3(2, B), 896, 0, stream>>>(
                SSH, SSL, H0[p0], H1[p1], ruB, zcatB);
            cand_cell<64, 128, 4, 8, true><<<dim3(BN / 64, 2), 256, 0, stream>>>(
                zcatB, H0[p0], H1[p1], ruB, (short8*)Wch[1], (short8*)Wcl[1], Wt[1][3], H1[p1 ^ 1]);
            p1 ^= 1;
        }
    }

    // -------- decoder (sequential; L1 D2 computes h-cols only) --------
    for (int hz = 0; hz < HZ; ++hz) {
        diffuse_solo<1, 65, 160, false, 0, false><<<dim3(3, B), 896, 0, stream>>>(
            SSH, SSL, dec_in, H0[p0], nullptr, zcatB);
        gate_cell<1, 65, 3, 5, false><<<dim3(BN / 64, 2), 256, 0, stream>>>(
            zcatB, dec_in, H0[p0], (short8*)Wgh[2], (short8*)Wgl[2], Wt[2][1], ruA);
        diffuse_solo<1, 65, 160, true, 0, false><<<dim3(3, B), 896, 0, stream>>>(
            SSH, SSL, dec_in, H0[p0], ruA, zcatB);
        cand_cell<1, 65, 3, 5, false><<<dim3(BN / 64, 2), 256, 0, stream>>>(
            zcatB, dec_in, H0[p0], ruA, (short8*)Wch[2], (short8*)Wcl[2], Wt[2][3], H0[p0 ^ 1]);
        p0 ^= 1;
        diffuse_solo<64, 128, 256, false, 0, true><<<dim3(4, B), 896, 0, stream>>>(
            SSH, SSL, H0[p0], H1[p1], nullptr, zcatB);
        gate_cell<64, 128, 4, 8, true><<<dim3(BN / 64, 2), 256, 0, stream>>>(
            zcatB, H0[p0], H1[p1], (short8*)Wgh[3], (short8*)Wgl[3], Wt[3][1], ruA);
        diffuse_solo<64, 128, 256, true, 2, true><<<dim3(2, B), 896, 0, stream>>>(
            SSH, SSL, H0[p0], H1[p1], ruA, zcatB);
        cand_proj<<<BN / 64, 256, 0, stream>>>(
            zcatB, H0[p0], H1[p1], ruA, (short8*)Wch[3], (short8*)Wcl[3], Wt[3][3],
            H1[p1 ^ 1], pW, pb, out + (size_t)hz * BN, dec_in);
        p1 ^= 1;
    }
}